// Round 1
// baseline (2062.308 us; speedup 1.0000x reference)
//
#include <hip/hip_runtime.h>
#include <hip/hip_bf16.h>

typedef __attribute__((ext_vector_type(4))) float f32x4;
typedef __attribute__((ext_vector_type(8))) short short8;

#define DEVFN __device__ __forceinline__

static constexpr int Bn = 16, Tn = 512, Sn = 512, Vn = 10000, En = 512, Hn = 1024, Ln = 6;
static constexpr int Mn = Bn * Tn;  // 8192 token rows
static constexpr float kScale = 0.70710678118654752440f;

DEVFN float bf2f(__hip_bfloat16 x) { return __bfloat162float(x); }
DEVFN __hip_bfloat16 f2bf(float x) { return __float2bfloat16(x); }

struct bf16x4 { __hip_bfloat16 x, y, z, w; };

// ---------------- small prep kernels ----------------

__global__ void padfill_kernel(__hip_bfloat16* p) {
    p[threadIdx.x] = f2bf(1.0f);  // PAD_VAL as float, per torch code
}

// embedded[b,t,:] = tok_emb[tgt[b,t],:] + pos_emb[t,:]   (bf16 out)
__global__ void embed_kernel(const int* __restrict__ tgt, const float* __restrict__ tok,
                             const float* __restrict__ pos, __hip_bfloat16* __restrict__ out) {
    int row = blockIdx.x;              // 0..8191
    int t = row & (Tn - 1);
    int v = tgt[row];
    const float* tr = tok + (long)v * En;
    const float* pr = pos + (long)t * En;
    __hip_bfloat16* orow = out + (long)row * En;
    int e = threadIdx.x * 4;           // block 128 covers 512
    float4 a = *(const float4*)(tr + e);
    float4 b = *(const float4*)(pr + e);
    bf16x4 o{f2bf(a.x + b.x), f2bf(a.y + b.y), f2bf(a.z + b.z), f2bf(a.w + b.w)};
    *(bf16x4*)(orow + e) = o;
}

// dst[c][r] = bf16(src[r][c]); src is [R][C] f32. grid(ceil(C/32), ceil(R/32), Z), block(32,8)
__global__ void transpose_f32_bf16(const float* __restrict__ src, __hip_bfloat16* __restrict__ dst,
                                   int R, int C, long sZi, long sZo) {
    __shared__ float tile[32][33];
    src += (long)blockIdx.z * sZi;
    dst += (long)blockIdx.z * sZo;
    int c0 = blockIdx.x * 32, r0 = blockIdx.y * 32;
    for (int i = threadIdx.y; i < 32; i += 8) {
        int r = r0 + i, c = c0 + threadIdx.x;
        tile[i][threadIdx.x] = (r < R && c < C) ? src[(long)r * C + c] : 0.f;
    }
    __syncthreads();
    for (int i = threadIdx.y; i < 32; i += 8) {
        int c = c0 + i, r = r0 + threadIdx.x;
        if (c < C && r < R) dst[(long)c * R + r] = f2bf(tile[threadIdx.x][i]);
    }
}

// plain f32 -> bf16 convert (n divisible by 4)
__global__ void convert_bf16_kernel(const float* __restrict__ src, __hip_bfloat16* __restrict__ dst, long n4) {
    long i = (long)blockIdx.x * blockDim.x + threadIdx.x;
    if (i >= n4) return;
    long j = i * 4;
    float4 v = *(const float4*)(src + j);
    bf16x4 o{f2bf(v.x), f2bf(v.y), f2bf(v.z), f2bf(v.w)};
    *(bf16x4*)(dst + j) = o;
}

// conv weight pack for layer l: wp[o][tap*H+i] = bf16(conv_w[l][o][i][tap])
// pure within-row permutation of the [2H, H*K] view. grid(12, 2048), block 256.
__global__ void wpack_kernel(const float* __restrict__ convw, __hip_bfloat16* __restrict__ wp, int l) {
    int kk = blockIdx.x * 256 + threadIdx.x;  // 0..3071
    int o = blockIdx.y;                        // 0..2047
    int i = kk & (Hn - 1);
    int tap = kk >> 10;
    long base = ((long)(l * 2 * Hn + o)) * (Hn * 3);
    wp[(long)o * (3 * Hn) + kk] = f2bf(convw[base + (long)i * 3 + tap]);
}

// GLU: out[m][j] = pre[m][j] * sigmoid(pre[m][H+j]); 4 elems/thread
__global__ void glu_kernel(const __hip_bfloat16* __restrict__ pre, __hip_bfloat16* __restrict__ out) {
    long idx = (long)blockIdx.x * blockDim.x + threadIdx.x;
    long j4 = idx * 4;
    if (j4 >= (long)Mn * Hn) return;
    int m = (int)(j4 >> 10);
    int j = (int)(j4 & (Hn - 1));
    bf16x4 a = *(const bf16x4*)(pre + (long)m * 2 * Hn + j);
    bf16x4 g = *(const bf16x4*)(pre + (long)m * 2 * Hn + Hn + j);
    bf16x4 o;
    o.x = f2bf(bf2f(a.x) * (1.f / (1.f + __expf(-bf2f(g.x)))));
    o.y = f2bf(bf2f(a.y) * (1.f / (1.f + __expf(-bf2f(g.y)))));
    o.z = f2bf(bf2f(a.z) * (1.f / (1.f + __expf(-bf2f(g.z)))));
    o.w = f2bf(bf2f(a.w) * (1.f / (1.f + __expf(-bf2f(g.w)))));
    *(bf16x4*)(out + j4) = o;
}

// row softmax over S=512; writes f32 (final attention output) + bf16 (next GEMM input)
__global__ __launch_bounds__(256) void softmax_kernel(const float* __restrict__ energy,
                                                      float* __restrict__ attn_f32,
                                                      __hip_bfloat16* __restrict__ attn_bf) {
    int row = blockIdx.x;  // 0..8191
    const float* e = energy + (long)row * Sn;
    int tid = threadIdx.x;
    float v0 = e[tid], v1 = e[tid + 256];
    float m = fmaxf(v0, v1);
    for (int off = 32; off; off >>= 1) m = fmaxf(m, __shfl_xor(m, off));
    __shared__ float redm[4];
    __shared__ float reds[4];
    int lane = tid & 63, w = tid >> 6;
    if (lane == 0) redm[w] = m;
    __syncthreads();
    m = fmaxf(fmaxf(redm[0], redm[1]), fmaxf(redm[2], redm[3]));
    float x0 = __expf(v0 - m), x1 = __expf(v1 - m);
    float s = x0 + x1;
    for (int off = 32; off; off >>= 1) s += __shfl_xor(s, off);
    if (lane == 0) reds[w] = s;
    __syncthreads();
    s = reds[0] + reds[1] + reds[2] + reds[3];
    float inv = 1.f / s;
    long base = (long)row * Sn;
    attn_f32[base + tid] = x0 * inv;
    attn_f32[base + tid + 256] = x1 * inv;
    attn_bf[base + tid] = f2bf(x0 * inv);
    attn_bf[base + tid + 256] = f2bf(x1 * inv);
}

// ---------------- the MFMA GEMM ----------------
// C[M,N] = A[M,K] @ B^T  where Bw is stored [N][K] bf16 (B-transposed / NT layout).
// 128x128 tile, BK=32, 4 waves, each wave 64x64 via 4x4 mfma_f32_16x16x32_bf16 frags.
// EPI: 0: x=acc+bias; 1: x=(acc+bias+R1)*s1; 2: x=((acc+bias+R1)*s1+R2)*s2
// IM2COL: A is conv_input [B*T][H]; virtual K=3*H with row shift m-2+tap, pad row for tau<0.
// NBOUND: guard B rows / C cols against N (fc_out N=10000).
template <int EPI, bool OUTF32, bool IM2COL, bool NBOUND>
__global__ __launch_bounds__(256) void gemm_bf16(
    const __hip_bfloat16* __restrict__ A, const __hip_bfloat16* __restrict__ Bw,
    const float* __restrict__ bias, void* __restrict__ Cout,
    const __hip_bfloat16* __restrict__ R1, const __hip_bfloat16* __restrict__ R2,
    const __hip_bfloat16* __restrict__ padrow,
    int M, int N, int K, long aZ, long bZ, long cZ, float s1, float s2) {
    __shared__ alignas(16) short As[128 * 32];
    __shared__ alignas(16) short Bs[128 * 32];
    const int tid = threadIdx.x;
    const int lane = tid & 63;
    const int wid = tid >> 6;
    const int wr = wid >> 1, wc = wid & 1;
    const int m0 = blockIdx.y * 128, n0 = blockIdx.x * 128;
    const short* Ag = (const short*)A + (long)blockIdx.z * aZ;
    const short* Bg = (const short*)Bw + (long)blockIdx.z * bZ;
    const short* pad = (const short*)padrow;

    f32x4 acc[4][4] = {};

    const int rc = tid >> 2;        // staging row (j=0)
    const int k8 = (tid & 3) * 8;   // element offset within the 32-wide row

    for (int k0 = 0; k0 < K; k0 += 32) {
        short8 av[2], bv[2];
#pragma unroll
        for (int j = 0; j < 2; ++j) {
            int r = rc + j * 64;
            const short* asrc;
            if (IM2COL) {
                int m = m0 + r;
                int t = m & (Tn - 1);
                int tap = k0 >> 10;
                int tau = t - 2 + tap;
                int kcol = (k0 & (Hn - 1)) + k8;
                asrc = (tau >= 0) ? (Ag + (long)(m - 2 + tap) * Hn + kcol) : (pad + k8);
            } else {
                asrc = Ag + (long)(m0 + r) * K + k0 + k8;
            }
            av[j] = *(const short8*)asrc;
            int n = n0 + r;
            const short* bsrc = (NBOUND && n >= N) ? (pad + k8) : (Bg + (long)n * K + k0 + k8);
            bv[j] = *(const short8*)bsrc;
        }
        __syncthreads();  // previous iteration's LDS reads done
#pragma unroll
        for (int j = 0; j < 2; ++j) {
            int r = rc + j * 64;
            *(short8*)&As[r * 32 + k8] = av[j];
            *(short8*)&Bs[r * 32 + k8] = bv[j];
        }
        __syncthreads();
        const int rsel = lane & 15, hi = (lane >> 4) * 8;
        short8 af[4], bg[4];
#pragma unroll
        for (int mi = 0; mi < 4; ++mi)
            af[mi] = *(const short8*)&As[(wr * 64 + mi * 16 + rsel) * 32 + hi];
#pragma unroll
        for (int ni = 0; ni < 4; ++ni)
            bg[ni] = *(const short8*)&Bs[(wc * 64 + ni * 16 + rsel) * 32 + hi];
#pragma unroll
        for (int mi = 0; mi < 4; ++mi)
#pragma unroll
            for (int ni = 0; ni < 4; ++ni)
                acc[mi][ni] = __builtin_amdgcn_mfma_f32_16x16x32_bf16(af[mi], bg[ni], acc[mi][ni], 0, 0, 0);
    }

    // epilogue: C/D layout col=lane&15, row=(lane>>4)*4+reg  [verified m89/m91]
    const int rsel = lane & 15, rg = (lane >> 4) * 4;
    float* Cf = (float*)Cout + (long)blockIdx.z * cZ;
    __hip_bfloat16* Cb = (__hip_bfloat16*)Cout + (long)blockIdx.z * cZ;
#pragma unroll
    for (int ni = 0; ni < 4; ++ni) {
        int col = n0 + wc * 64 + ni * 16 + rsel;
        if (NBOUND && col >= N) continue;
        float bi = bias ? bias[col] : 0.f;
#pragma unroll
        for (int mi = 0; mi < 4; ++mi) {
            int row = m0 + wr * 64 + mi * 16 + rg;
            f32x4 v = acc[mi][ni];
#pragma unroll
            for (int q = 0; q < 4; ++q) {
                long idx = (long)(row + q) * N + col;
                float x = v[q] + bi;
                if (EPI >= 1) x = (x + bf2f(R1[idx])) * s1;
                if (EPI >= 2) x = (x + bf2f(R2[idx])) * s2;
                if (OUTF32) Cf[idx] = x;
                else Cb[idx] = f2bf(x);
            }
        }
    }
}

// ---------------- launcher ----------------

extern "C" void kernel_launch(void* const* d_in, const int* in_sizes, int n_in,
                              void* d_out, int out_size, void* d_ws, size_t ws_size,
                              hipStream_t stream) {
    const int* tgt = (const int*)d_in[0];
    const float* enc_conved = (const float*)d_in[1];
    const float* enc_combined = (const float*)d_in[2];
    const float* tok_emb = (const float*)d_in[3];
    const float* pos_emb = (const float*)d_in[4];
    const float* w_e2h = (const float*)d_in[5];
    const float* b_e2h = (const float*)d_in[6];
    const float* w_h2e = (const float*)d_in[7];
    const float* b_h2e = (const float*)d_in[8];
    const float* w_ah2e = (const float*)d_in[9];
    const float* b_ah2e = (const float*)d_in[10];
    const float* w_ae2h = (const float*)d_in[11];
    const float* b_ae2h = (const float*)d_in[12];
    const float* w_fc = (const float*)d_in[13];
    const float* b_fc = (const float*)d_in[14];
    const float* conv_w = (const float*)d_in[15];
    const float* conv_b = (const float*)d_in[16];

    char* ws = (char*)d_ws;
    size_t off = 0;
    auto alloc = [&](size_t bytes) { size_t r = off; off = (off + bytes + 255) & ~(size_t)255; return r; };
    __hip_bfloat16* emb    = (__hip_bfloat16*)(ws + alloc((size_t)Mn * En * 2));        // 8.4 MB
    __hip_bfloat16* convin = (__hip_bfloat16*)(ws + alloc((size_t)Mn * Hn * 2));        // 16.8 MB
    size_t o_pre = alloc((size_t)Mn * 2 * Hn * 2);                                      // 33.6 MB
    __hip_bfloat16* pre = (__hip_bfloat16*)(ws + o_pre);
    float* energy = (float*)(ws + o_pre);                        // overlays pre (dead after GLU)
    __hip_bfloat16* attnbf = (__hip_bfloat16*)(ws + o_pre + (size_t)Mn * Sn * 4);
    __hip_bfloat16* conved = (__hip_bfloat16*)(ws + alloc((size_t)Mn * Hn * 2));        // 16.8 MB
    __hip_bfloat16* tmpE   = (__hip_bfloat16*)(ws + alloc((size_t)Mn * En * 2));        // 8.4 MB
    __hip_bfloat16* wT_e2h = (__hip_bfloat16*)(ws + alloc((size_t)Hn * En * 2));
    __hip_bfloat16* wT_h2e = (__hip_bfloat16*)(ws + alloc((size_t)En * Hn * 2));
    __hip_bfloat16* wT_ah2e= (__hip_bfloat16*)(ws + alloc((size_t)En * Hn * 2));
    __hip_bfloat16* wT_ae2h= (__hip_bfloat16*)(ws + alloc((size_t)Hn * En * 2));
    __hip_bfloat16* wT_fc  = (__hip_bfloat16*)(ws + alloc((size_t)Vn * En * 2));        // 10.2 MB
    __hip_bfloat16* wpack  = (__hip_bfloat16*)(ws + alloc((size_t)2 * Hn * 3 * Hn * 2));// 25.2 MB
    __hip_bfloat16* encc   = (__hip_bfloat16*)(ws + alloc((size_t)Bn * Sn * En * 2));   // 8.4 MB
    __hip_bfloat16* encTc  = (__hip_bfloat16*)(ws + alloc((size_t)Bn * En * Sn * 2));   // 8.4 MB
    __hip_bfloat16* padrow = (__hip_bfloat16*)(ws + alloc(256));

    float* out = (float*)d_out;
    float* attn_out = out + (long)Mn * Vn;
    const long bSq = (long)Sn * Sn;  // 262144, per-batch stride for T=S=E=512 blocks

    dim3 tb(32, 8);

    // ---- prep ----
    padfill_kernel<<<1, 128, 0, stream>>>(padrow);
    embed_kernel<<<Mn, 128, 0, stream>>>(tgt, tok_emb, pos_emb, emb);
    transpose_f32_bf16<<<dim3(Hn / 32, En / 32, 1), tb, 0, stream>>>(w_e2h, wT_e2h, En, Hn, 0, 0);
    transpose_f32_bf16<<<dim3(En / 32, Hn / 32, 1), tb, 0, stream>>>(w_h2e, wT_h2e, Hn, En, 0, 0);
    transpose_f32_bf16<<<dim3(En / 32, Hn / 32, 1), tb, 0, stream>>>(w_ah2e, wT_ah2e, Hn, En, 0, 0);
    transpose_f32_bf16<<<dim3(Hn / 32, En / 32, 1), tb, 0, stream>>>(w_ae2h, wT_ae2h, En, Hn, 0, 0);
    transpose_f32_bf16<<<dim3((Vn + 31) / 32, En / 32, 1), tb, 0, stream>>>(w_fc, wT_fc, En, Vn, 0, 0);
    transpose_f32_bf16<<<dim3(En / 32, Sn / 32, Bn), tb, 0, stream>>>(enc_combined, encTc, Sn, En, bSq, bSq);
    convert_bf16_kernel<<<((long)Bn * Sn * En / 4 + 255) / 256, 256, 0, stream>>>(enc_conved, encc, (long)Bn * Sn * En / 4);

    // conv_input = embedded @ emb2hid + b       [8192,1024]
    gemm_bf16<0, false, false, false><<<dim3(Hn / 128, Mn / 128, 1), 256, 0, stream>>>(
        emb, wT_e2h, b_e2h, convin, nullptr, nullptr, padrow, Mn, Hn, En, 0, 0, 0, 1.f, 1.f);

    for (int l = 0; l < Ln; ++l) {
        // pack conv weight for this layer (within-row permutation, f32->bf16)
        wpack_kernel<<<dim3(3 * Hn / 256, 2 * Hn, 1), 256, 0, stream>>>(conv_w, wpack, l);
        // pre = im2col(conv_input) @ wpack^T + conv_b[l]    [8192,2048], K=3072
        gemm_bf16<0, false, true, false><<<dim3(2 * Hn / 128, Mn / 128, 1), 256, 0, stream>>>(
            convin, wpack, conv_b + (long)l * 2 * Hn, pre, nullptr, nullptr, padrow,
            Mn, 2 * Hn, 3 * Hn, 0, 0, 0, 1.f, 1.f);
        // conved = GLU(pre)
        glu_kernel<<<(Mn * Hn / 4) / 256, 256, 0, stream>>>(pre, conved);
        // combined = (conved @ attn_hid2emb + b + embedded) * scale   [8192,512]
        gemm_bf16<1, false, false, false><<<dim3(En / 128, Mn / 128, 1), 256, 0, stream>>>(
            conved, wT_ah2e, b_ah2e, tmpE, emb, nullptr, padrow, Mn, En, Hn, 0, 0, 0, kScale, 1.f);
        // energy[b] = combined[b] @ enc_conved[b]^T   (batched NT, f32 out)
        gemm_bf16<0, true, false, false><<<dim3(Sn / 128, Tn / 128, Bn), 256, 0, stream>>>(
            tmpE, encc, nullptr, energy, nullptr, nullptr, padrow, Tn, Sn, En, bSq, bSq, bSq, 1.f, 1.f);
        // attention = softmax(energy)  -> d_out tail (f32) + bf16 scratch
        softmax_kernel<<<Mn, 256, 0, stream>>>(energy, attn_out, attnbf);
        // attended[b] = attention[b] @ enc_combined[b]   (batched, B pre-transposed)
        gemm_bf16<0, false, false, false><<<dim3(En / 128, Tn / 128, Bn), 256, 0, stream>>>(
            attnbf, encTc, nullptr, tmpE, nullptr, nullptr, padrow, Tn, En, Sn, bSq, bSq, bSq, 1.f, 1.f);
        // conv_input = ((attended @ attn_emb2hid + b + conved)*scale + conv_input)*scale
        gemm_bf16<2, false, false, false><<<dim3(Hn / 128, Mn / 128, 1), 256, 0, stream>>>(
            tmpE, wT_ae2h, b_ae2h, convin, conved, convin, padrow, Mn, Hn, En, 0, 0, 0, kScale, kScale);
    }

    // conved = conv_input @ hid2emb + b   [8192,512]
    gemm_bf16<0, false, false, false><<<dim3(En / 128, Mn / 128, 1), 256, 0, stream>>>(
        convin, wT_h2e, b_h2e, tmpE, nullptr, nullptr, padrow, Mn, En, Hn, 0, 0, 0, 1.f, 1.f);
    // output = conved @ fc_out + b        [8192,10000] f32, N-bounded
    gemm_bf16<0, true, false, true><<<dim3((Vn + 127) / 128, Mn / 128, 1), 256, 0, stream>>>(
        tmpE, wT_fc, b_fc, out, nullptr, nullptr, padrow, Mn, Vn, En, 0, 0, 0, 1.f, 1.f);
}

// Round 2
// 2031.608 us; speedup vs baseline: 1.0151x; 1.0151x over previous
//
#include <hip/hip_runtime.h>
#include <hip/hip_bf16.h>

typedef __attribute__((ext_vector_type(4))) float f32x4;
typedef __attribute__((ext_vector_type(8))) short short8;

#define DEVFN __device__ __forceinline__

static constexpr int Bn = 16, Tn = 512, Sn = 512, Vn = 10000, En = 512, Hn = 1024, Ln = 6;
static constexpr int Mn = Bn * Tn;  // 8192 token rows
static constexpr float kScale = 0.70710678118654752440f;

DEVFN float bf2f(__hip_bfloat16 x) { return __bfloat162float(x); }
DEVFN __hip_bfloat16 f2bf(float x) { return __float2bfloat16(x); }

struct bf16x4 { __hip_bfloat16 x, y, z, w; };

// async global -> LDS, 16B per lane (wave-uniform LDS base + lane*16 layout)
DEVFN void gload_lds16(const short* g, short* l) {
    __builtin_amdgcn_global_load_lds((const __attribute__((address_space(1))) void*)g,
                                     (__attribute__((address_space(3))) void*)l, 16, 0, 0);
}

// ---------------- small prep kernels ----------------

__global__ void padfill_kernel(__hip_bfloat16* p) {
    p[threadIdx.x] = f2bf(1.0f);  // PAD_VAL as float, per torch code
}

// embedded[b,t,:] = tok_emb[tgt[b,t],:] + pos_emb[t,:]   (bf16 out)
__global__ void embed_kernel(const int* __restrict__ tgt, const float* __restrict__ tok,
                             const float* __restrict__ pos, __hip_bfloat16* __restrict__ out) {
    int row = blockIdx.x;              // 0..8191
    int t = row & (Tn - 1);
    int v = tgt[row];
    const float* tr = tok + (long)v * En;
    const float* pr = pos + (long)t * En;
    __hip_bfloat16* orow = out + (long)row * En;
    int e = threadIdx.x * 4;           // block 128 covers 512
    float4 a = *(const float4*)(tr + e);
    float4 b = *(const float4*)(pr + e);
    bf16x4 o{f2bf(a.x + b.x), f2bf(a.y + b.y), f2bf(a.z + b.z), f2bf(a.w + b.w)};
    *(bf16x4*)(orow + e) = o;
}

// dst[c][r] = bf16(src[r][c]); src is [R][C] f32. grid(ceil(C/32), ceil(R/32), Z), block(32,8)
__global__ void transpose_f32_bf16(const float* __restrict__ src, __hip_bfloat16* __restrict__ dst,
                                   int R, int C, long sZi, long sZo) {
    __shared__ float tile[32][33];
    src += (long)blockIdx.z * sZi;
    dst += (long)blockIdx.z * sZo;
    int c0 = blockIdx.x * 32, r0 = blockIdx.y * 32;
    for (int i = threadIdx.y; i < 32; i += 8) {
        int r = r0 + i, c = c0 + threadIdx.x;
        tile[i][threadIdx.x] = (r < R && c < C) ? src[(long)r * C + c] : 0.f;
    }
    __syncthreads();
    for (int i = threadIdx.y; i < 32; i += 8) {
        int c = c0 + i, r = r0 + threadIdx.x;
        if (c < C && r < R) dst[(long)c * R + r] = f2bf(tile[threadIdx.x][i]);
    }
}

// plain f32 -> bf16 convert (n divisible by 4)
__global__ void convert_bf16_kernel(const float* __restrict__ src, __hip_bfloat16* __restrict__ dst, long n4) {
    long i = (long)blockIdx.x * blockDim.x + threadIdx.x;
    if (i >= n4) return;
    long j = i * 4;
    float4 v = *(const float4*)(src + j);
    bf16x4 o{f2bf(v.x), f2bf(v.y), f2bf(v.z), f2bf(v.w)};
    *(bf16x4*)(dst + j) = o;
}

// conv weight pack for layer l: wp[o][tap*H+i] = bf16(conv_w[l][o][i][tap])
// pure within-row permutation of the [2H, H*K] view. grid(12, 2048), block 256.
__global__ void wpack_kernel(const float* __restrict__ convw, __hip_bfloat16* __restrict__ wp, int l) {
    int kk = blockIdx.x * 256 + threadIdx.x;  // 0..3071
    int o = blockIdx.y;                        // 0..2047
    int i = kk & (Hn - 1);
    int tap = kk >> 10;
    long base = ((long)(l * 2 * Hn + o)) * (Hn * 3);
    wp[(long)o * (3 * Hn) + kk] = f2bf(convw[base + (long)i * 3 + tap]);
}

// GLU: out[m][j] = pre[m][j] * sigmoid(pre[m][H+j]); 4 elems/thread
__global__ void glu_kernel(const __hip_bfloat16* __restrict__ pre, __hip_bfloat16* __restrict__ out) {
    long idx = (long)blockIdx.x * blockDim.x + threadIdx.x;
    long j4 = idx * 4;
    if (j4 >= (long)Mn * Hn) return;
    int m = (int)(j4 >> 10);
    int j = (int)(j4 & (Hn - 1));
    bf16x4 a = *(const bf16x4*)(pre + (long)m * 2 * Hn + j);
    bf16x4 g = *(const bf16x4*)(pre + (long)m * 2 * Hn + Hn + j);
    bf16x4 o;
    o.x = f2bf(bf2f(a.x) * (1.f / (1.f + __expf(-bf2f(g.x)))));
    o.y = f2bf(bf2f(a.y) * (1.f / (1.f + __expf(-bf2f(g.y)))));
    o.z = f2bf(bf2f(a.z) * (1.f / (1.f + __expf(-bf2f(g.z)))));
    o.w = f2bf(bf2f(a.w) * (1.f / (1.f + __expf(-bf2f(g.w)))));
    *(bf16x4*)(out + j4) = o;
}

// row softmax over S=512; writes bf16 (next GEMM input) + optional f32 (final attention)
__global__ __launch_bounds__(256) void softmax_kernel(const float* __restrict__ energy,
                                                      float* __restrict__ attn_f32,
                                                      __hip_bfloat16* __restrict__ attn_bf) {
    int row = blockIdx.x;  // 0..8191
    const float* e = energy + (long)row * Sn;
    int tid = threadIdx.x;
    float v0 = e[tid], v1 = e[tid + 256];
    float m = fmaxf(v0, v1);
    for (int off = 32; off; off >>= 1) m = fmaxf(m, __shfl_xor(m, off));
    __shared__ float redm[4];
    __shared__ float reds[4];
    int lane = tid & 63, w = tid >> 6;
    if (lane == 0) redm[w] = m;
    __syncthreads();
    m = fmaxf(fmaxf(redm[0], redm[1]), fmaxf(redm[2], redm[3]));
    float x0 = __expf(v0 - m), x1 = __expf(v1 - m);
    float s = x0 + x1;
    for (int off = 32; off; off >>= 1) s += __shfl_xor(s, off);
    if (lane == 0) reds[w] = s;
    __syncthreads();
    s = reds[0] + reds[1] + reds[2] + reds[3];
    float inv = 1.f / s;
    long base = (long)row * Sn;
    if (attn_f32) {
        attn_f32[base + tid] = x0 * inv;
        attn_f32[base + tid + 256] = x1 * inv;
    }
    attn_bf[base + tid] = f2bf(x0 * inv);
    attn_bf[base + tid + 256] = f2bf(x1 * inv);
}

// ---------------- the MFMA GEMM ----------------
// C[M,N] = A[M,K] @ B^T  where Bw is stored [N][K] bf16 (B-transposed / NT layout).
// 128x128 tile, BK=32, 4 waves, each wave 64x64 via 4x4 mfma_f32_16x16x32_bf16 frags.
// Staging via global_load_lds width=16 (m97 structure): LDS dst = wavebase + lane*16B,
// which the linear [128][32] layout provides (byte off = w*1024 + l*16 per j-half).
// EPI: 0: x=acc+bias; 1: x=(acc+bias+R1)*s1; 2: x=((acc+bias+R1)*s1+R2)*s2
// IM2COL: A is conv_input [B*T][H]; virtual K=3*H with row shift m-2+tap, pad row for tau<0.
// NBOUND: guard B rows / C cols against N (fc_out N=10000).
template <int EPI, bool OUTF32, bool IM2COL, bool NBOUND>
__global__ __launch_bounds__(256) void gemm_bf16(
    const __hip_bfloat16* __restrict__ A, const __hip_bfloat16* __restrict__ Bw,
    const float* __restrict__ bias, void* __restrict__ Cout,
    const __hip_bfloat16* __restrict__ R1, const __hip_bfloat16* __restrict__ R2,
    const __hip_bfloat16* __restrict__ padrow,
    int M, int N, int K, long aZ, long bZ, long cZ, float s1, float s2) {
    __shared__ alignas(16) short As[128 * 32];
    __shared__ alignas(16) short Bs[128 * 32];
    const int tid = threadIdx.x;
    const int lane = tid & 63;
    const int wid = tid >> 6;
    const int wr = wid >> 1, wc = wid & 1;
    const int m0 = blockIdx.y * 128, n0 = blockIdx.x * 128;
    const short* Ag = (const short*)A + (long)blockIdx.z * aZ;
    const short* Bg = (const short*)Bw + (long)blockIdx.z * bZ;
    const short* pad = (const short*)padrow;

    f32x4 acc[4][4] = {};

    const int rc = tid >> 2;        // staging row (j=0)
    const int k8 = (tid & 3) * 8;   // element offset within the 32-wide row

    for (int k0 = 0; k0 < K; k0 += 32) {
        __syncthreads();  // previous iteration's LDS reads complete before overwrite
#pragma unroll
        for (int j = 0; j < 2; ++j) {
            int r = rc + j * 64;
            const short* asrc;
            if (IM2COL) {
                int m = m0 + r;
                int t = m & (Tn - 1);
                int tap = k0 >> 10;
                int tau = t - 2 + tap;
                int kcol = (k0 & (Hn - 1)) + k8;
                asrc = (tau >= 0) ? (Ag + (long)(m - 2 + tap) * Hn + kcol) : (pad + k8);
            } else {
                asrc = Ag + (long)(m0 + r) * K + k0 + k8;
            }
            gload_lds16(asrc, &As[r * 32 + k8]);
            int n = n0 + r;
            const short* bsrc = (NBOUND && n >= N) ? (pad + k8) : (Bg + (long)n * K + k0 + k8);
            gload_lds16(bsrc, &Bs[r * 32 + k8]);
        }
        __syncthreads();  // vmcnt(0) drain + barrier: staged tile visible to all waves
        const int rsel = lane & 15, hi = (lane >> 4) * 8;
        short8 af[4], bg[4];
#pragma unroll
        for (int mi = 0; mi < 4; ++mi)
            af[mi] = *(const short8*)&As[(wr * 64 + mi * 16 + rsel) * 32 + hi];
#pragma unroll
        for (int ni = 0; ni < 4; ++ni)
            bg[ni] = *(const short8*)&Bs[(wc * 64 + ni * 16 + rsel) * 32 + hi];
#pragma unroll
        for (int mi = 0; mi < 4; ++mi)
#pragma unroll
            for (int ni = 0; ni < 4; ++ni)
                acc[mi][ni] = __builtin_amdgcn_mfma_f32_16x16x32_bf16(af[mi], bg[ni], acc[mi][ni], 0, 0, 0);
    }

    // epilogue: C/D layout col=lane&15, row=(lane>>4)*4+reg  [verified m89/m91]
    const int rsel = lane & 15, rg = (lane >> 4) * 4;
    float* Cf = (float*)Cout + (long)blockIdx.z * cZ;
    __hip_bfloat16* Cb = (__hip_bfloat16*)Cout + (long)blockIdx.z * cZ;
#pragma unroll
    for (int ni = 0; ni < 4; ++ni) {
        int col = n0 + wc * 64 + ni * 16 + rsel;
        if (NBOUND && col >= N) continue;
        float bi = bias ? bias[col] : 0.f;
#pragma unroll
        for (int mi = 0; mi < 4; ++mi) {
            int row = m0 + wr * 64 + mi * 16 + rg;
            f32x4 v = acc[mi][ni];
#pragma unroll
            for (int q = 0; q < 4; ++q) {
                long idx = (long)(row + q) * N + col;
                float x = v[q] + bi;
                if (EPI >= 1) x = (x + bf2f(R1[idx])) * s1;
                if (EPI >= 2) x = (x + bf2f(R2[idx])) * s2;
                if (OUTF32) Cf[idx] = x;
                else Cb[idx] = f2bf(x);
            }
        }
    }
}

// ---------------- launcher ----------------

extern "C" void kernel_launch(void* const* d_in, const int* in_sizes, int n_in,
                              void* d_out, int out_size, void* d_ws, size_t ws_size,
                              hipStream_t stream) {
    const int* tgt = (const int*)d_in[0];
    const float* enc_conved = (const float*)d_in[1];
    const float* enc_combined = (const float*)d_in[2];
    const float* tok_emb = (const float*)d_in[3];
    const float* pos_emb = (const float*)d_in[4];
    const float* w_e2h = (const float*)d_in[5];
    const float* b_e2h = (const float*)d_in[6];
    const float* w_h2e = (const float*)d_in[7];
    const float* b_h2e = (const float*)d_in[8];
    const float* w_ah2e = (const float*)d_in[9];
    const float* b_ah2e = (const float*)d_in[10];
    const float* w_ae2h = (const float*)d_in[11];
    const float* b_ae2h = (const float*)d_in[12];
    const float* w_fc = (const float*)d_in[13];
    const float* b_fc = (const float*)d_in[14];
    const float* conv_w = (const float*)d_in[15];
    const float* conv_b = (const float*)d_in[16];

    char* ws = (char*)d_ws;
    size_t off = 0;
    auto alloc = [&](size_t bytes) { size_t r = off; off = (off + bytes + 255) & ~(size_t)255; return r; };
    __hip_bfloat16* emb    = (__hip_bfloat16*)(ws + alloc((size_t)Mn * En * 2));        // 8.4 MB
    __hip_bfloat16* convin = (__hip_bfloat16*)(ws + alloc((size_t)Mn * Hn * 2));        // 16.8 MB
    size_t o_pre = alloc((size_t)Mn * 2 * Hn * 2);                                      // 33.6 MB
    __hip_bfloat16* pre = (__hip_bfloat16*)(ws + o_pre);
    float* energy = (float*)(ws + o_pre);                        // overlays pre (dead after GLU)
    __hip_bfloat16* attnbf = (__hip_bfloat16*)(ws + o_pre + (size_t)Mn * Sn * 4);
    __hip_bfloat16* conved = (__hip_bfloat16*)(ws + alloc((size_t)Mn * Hn * 2));        // 16.8 MB
    __hip_bfloat16* tmpE   = (__hip_bfloat16*)(ws + alloc((size_t)Mn * En * 2));        // 8.4 MB
    __hip_bfloat16* wT_e2h = (__hip_bfloat16*)(ws + alloc((size_t)Hn * En * 2));
    __hip_bfloat16* wT_h2e = (__hip_bfloat16*)(ws + alloc((size_t)En * Hn * 2));
    __hip_bfloat16* wT_ah2e= (__hip_bfloat16*)(ws + alloc((size_t)En * Hn * 2));
    __hip_bfloat16* wT_ae2h= (__hip_bfloat16*)(ws + alloc((size_t)Hn * En * 2));
    __hip_bfloat16* wT_fc  = (__hip_bfloat16*)(ws + alloc((size_t)Vn * En * 2));        // 10.2 MB
    __hip_bfloat16* wpack  = (__hip_bfloat16*)(ws + alloc((size_t)2 * Hn * 3 * Hn * 2));// 25.2 MB
    __hip_bfloat16* encc   = (__hip_bfloat16*)(ws + alloc((size_t)Bn * Sn * En * 2));   // 8.4 MB
    __hip_bfloat16* encTc  = (__hip_bfloat16*)(ws + alloc((size_t)Bn * En * Sn * 2));   // 8.4 MB
    __hip_bfloat16* padrow = (__hip_bfloat16*)(ws + alloc(256));

    float* out = (float*)d_out;
    float* attn_out = out + (long)Mn * Vn;
    const long bSq = (long)Sn * Sn;  // 262144, per-batch stride for T=S=E=512 blocks

    dim3 tb(32, 8);

    // ---- prep ----
    padfill_kernel<<<1, 128, 0, stream>>>(padrow);
    embed_kernel<<<Mn, 128, 0, stream>>>(tgt, tok_emb, pos_emb, emb);
    transpose_f32_bf16<<<dim3(Hn / 32, En / 32, 1), tb, 0, stream>>>(w_e2h, wT_e2h, En, Hn, 0, 0);
    transpose_f32_bf16<<<dim3(En / 32, Hn / 32, 1), tb, 0, stream>>>(w_h2e, wT_h2e, Hn, En, 0, 0);
    transpose_f32_bf16<<<dim3(En / 32, Hn / 32, 1), tb, 0, stream>>>(w_ah2e, wT_ah2e, Hn, En, 0, 0);
    transpose_f32_bf16<<<dim3(Hn / 32, En / 32, 1), tb, 0, stream>>>(w_ae2h, wT_ae2h, En, Hn, 0, 0);
    transpose_f32_bf16<<<dim3((Vn + 31) / 32, En / 32, 1), tb, 0, stream>>>(w_fc, wT_fc, En, Vn, 0, 0);
    transpose_f32_bf16<<<dim3(En / 32, Sn / 32, Bn), tb, 0, stream>>>(enc_combined, encTc, Sn, En, bSq, bSq);
    convert_bf16_kernel<<<((long)Bn * Sn * En / 4 + 255) / 256, 256, 0, stream>>>(enc_conved, encc, (long)Bn * Sn * En / 4);

    // conv_input = embedded @ emb2hid + b       [8192,1024]
    gemm_bf16<0, false, false, false><<<dim3(Hn / 128, Mn / 128, 1), 256, 0, stream>>>(
        emb, wT_e2h, b_e2h, convin, nullptr, nullptr, padrow, Mn, Hn, En, 0, 0, 0, 1.f, 1.f);

    for (int l = 0; l < Ln; ++l) {
        // pack conv weight for this layer (within-row permutation, f32->bf16)
        wpack_kernel<<<dim3(3 * Hn / 256, 2 * Hn, 1), 256, 0, stream>>>(conv_w, wpack, l);
        // pre = im2col(conv_input) @ wpack^T + conv_b[l]    [8192,2048], K=3072
        gemm_bf16<0, false, true, false><<<dim3(2 * Hn / 128, Mn / 128, 1), 256, 0, stream>>>(
            convin, wpack, conv_b + (long)l * 2 * Hn, pre, nullptr, nullptr, padrow,
            Mn, 2 * Hn, 3 * Hn, 0, 0, 0, 1.f, 1.f);
        // conved = GLU(pre)
        glu_kernel<<<(Mn * Hn / 4) / 256, 256, 0, stream>>>(pre, conved);
        // combined = (conved @ attn_hid2emb + b + embedded) * scale   [8192,512]
        gemm_bf16<1, false, false, false><<<dim3(En / 128, Mn / 128, 1), 256, 0, stream>>>(
            conved, wT_ah2e, b_ah2e, tmpE, emb, nullptr, padrow, Mn, En, Hn, 0, 0, 0, kScale, 1.f);
        // energy[b] = combined[b] @ enc_conved[b]^T   (batched NT, f32 out)
        gemm_bf16<0, true, false, false><<<dim3(Sn / 128, Tn / 128, Bn), 256, 0, stream>>>(
            tmpE, encc, nullptr, energy, nullptr, nullptr, padrow, Tn, Sn, En, bSq, bSq, bSq, 1.f, 1.f);
        // attention = softmax(energy)  (f32 out only needed from the LAST layer)
        softmax_kernel<<<Mn, 256, 0, stream>>>(energy, (l == Ln - 1) ? attn_out : nullptr, attnbf);
        // attended[b] = attention[b] @ enc_combined[b]   (batched, B pre-transposed)
        gemm_bf16<0, false, false, false><<<dim3(En / 128, Tn / 128, Bn), 256, 0, stream>>>(
            attnbf, encTc, nullptr, tmpE, nullptr, nullptr, padrow, Tn, En, Sn, bSq, bSq, bSq, 1.f, 1.f);
        // conv_input = ((attended @ attn_emb2hid + b + conved)*scale + conv_input)*scale
        gemm_bf16<2, false, false, false><<<dim3(Hn / 128, Mn / 128, 1), 256, 0, stream>>>(
            tmpE, wT_ae2h, b_ae2h, convin, conved, convin, padrow, Mn, Hn, En, 0, 0, 0, kScale, kScale);
    }

    // conved = conv_input @ hid2emb + b   [8192,512]
    gemm_bf16<0, false, false, false><<<dim3(En / 128, Mn / 128, 1), 256, 0, stream>>>(
        convin, wT_h2e, b_h2e, tmpE, nullptr, nullptr, padrow, Mn, En, Hn, 0, 0, 0, 1.f, 1.f);
    // output = conved @ fc_out + b        [8192,10000] f32, N-bounded
    gemm_bf16<0, true, false, true><<<dim3((Vn + 127) / 128, Mn / 128, 1), 256, 0, stream>>>(
        tmpE, wT_fc, b_fc, out, nullptr, nullptr, padrow, Mn, Vn, En, 0, 0, 0, 1.f, 1.f);
}

// Round 3
// 1905.724 us; speedup vs baseline: 1.0822x; 1.0661x over previous
//
#include <hip/hip_runtime.h>
#include <hip/hip_bf16.h>

typedef __attribute__((ext_vector_type(4))) float f32x4;
typedef __attribute__((ext_vector_type(8))) short short8;

#define DEVFN __device__ __forceinline__

static constexpr int Bn = 16, Tn = 512, Sn = 512, Vn = 10000, En = 512, Hn = 1024, Ln = 6;
static constexpr int Mn = Bn * Tn;  // 8192 token rows
static constexpr float kScale = 0.70710678118654752440f;

DEVFN float bf2f(__hip_bfloat16 x) { return __bfloat162float(x); }
DEVFN __hip_bfloat16 f2bf(float x) { return __float2bfloat16(x); }

struct bf16x4 { __hip_bfloat16 x, y, z, w; };

// async global -> LDS, 16B per lane (wave-uniform LDS base + lane*16 layout)
DEVFN void gload_lds16(const short* g, short* l) {
    __builtin_amdgcn_global_load_lds((const __attribute__((address_space(1))) void*)g,
                                     (__attribute__((address_space(3))) void*)l, 16, 0, 0);
}

// ---------------- small prep kernels ----------------

__global__ void padfill_kernel(__hip_bfloat16* p) {
    p[threadIdx.x] = f2bf(1.0f);  // PAD_VAL as float, per torch code
}

// embedded[b,t,:] = tok_emb[tgt[b,t],:] + pos_emb[t,:]   (bf16 out)
__global__ void embed_kernel(const int* __restrict__ tgt, const float* __restrict__ tok,
                             const float* __restrict__ pos, __hip_bfloat16* __restrict__ out) {
    int row = blockIdx.x;              // 0..8191
    int t = row & (Tn - 1);
    int v = tgt[row];
    const float* tr = tok + (long)v * En;
    const float* pr = pos + (long)t * En;
    __hip_bfloat16* orow = out + (long)row * En;
    int e = threadIdx.x * 4;           // block 128 covers 512
    float4 a = *(const float4*)(tr + e);
    float4 b = *(const float4*)(pr + e);
    bf16x4 o{f2bf(a.x + b.x), f2bf(a.y + b.y), f2bf(a.z + b.z), f2bf(a.w + b.w)};
    *(bf16x4*)(orow + e) = o;
}

// dst[c][r] = bf16(src[r][c]); src is [R][C] f32. grid(ceil(C/32), ceil(R/32), Z), block(32,8)
__global__ void transpose_f32_bf16(const float* __restrict__ src, __hip_bfloat16* __restrict__ dst,
                                   int R, int C, long sZi, long sZo) {
    __shared__ float tile[32][33];
    src += (long)blockIdx.z * sZi;
    dst += (long)blockIdx.z * sZo;
    int c0 = blockIdx.x * 32, r0 = blockIdx.y * 32;
    for (int i = threadIdx.y; i < 32; i += 8) {
        int r = r0 + i, c = c0 + threadIdx.x;
        tile[i][threadIdx.x] = (r < R && c < C) ? src[(long)r * C + c] : 0.f;
    }
    __syncthreads();
    for (int i = threadIdx.y; i < 32; i += 8) {
        int c = c0 + i, r = r0 + threadIdx.x;
        if (c < C && r < R) dst[(long)c * R + r] = f2bf(tile[threadIdx.x][i]);
    }
}

// plain f32 -> bf16 convert (n divisible by 4)
__global__ void convert_bf16_kernel(const float* __restrict__ src, __hip_bfloat16* __restrict__ dst, long n4) {
    long i = (long)blockIdx.x * blockDim.x + threadIdx.x;
    if (i >= n4) return;
    long j = i * 4;
    float4 v = *(const float4*)(src + j);
    bf16x4 o{f2bf(v.x), f2bf(v.y), f2bf(v.z), f2bf(v.w)};
    *(bf16x4*)(dst + j) = o;
}

// conv weight pack for layer l: wp[o][tap*H+i] = bf16(conv_w[l][o][i][tap])
// pure within-row permutation of the [2H, H*K] view. grid(12, 2048), block 256.
__global__ void wpack_kernel(const float* __restrict__ convw, __hip_bfloat16* __restrict__ wp, int l) {
    int kk = blockIdx.x * 256 + threadIdx.x;  // 0..3071
    int o = blockIdx.y;                        // 0..2047
    int i = kk & (Hn - 1);
    int tap = kk >> 10;
    long base = ((long)(l * 2 * Hn + o)) * (Hn * 3);
    wp[(long)o * (3 * Hn) + kk] = f2bf(convw[base + (long)i * 3 + tap]);
}

// GLU: out[m][j] = pre[m][j] * sigmoid(pre[m][H+j]); 4 elems/thread
__global__ void glu_kernel(const __hip_bfloat16* __restrict__ pre, __hip_bfloat16* __restrict__ out) {
    long idx = (long)blockIdx.x * blockDim.x + threadIdx.x;
    long j4 = idx * 4;
    if (j4 >= (long)Mn * Hn) return;
    int m = (int)(j4 >> 10);
    int j = (int)(j4 & (Hn - 1));
    bf16x4 a = *(const bf16x4*)(pre + (long)m * 2 * Hn + j);
    bf16x4 g = *(const bf16x4*)(pre + (long)m * 2 * Hn + Hn + j);
    bf16x4 o;
    o.x = f2bf(bf2f(a.x) * (1.f / (1.f + __expf(-bf2f(g.x)))));
    o.y = f2bf(bf2f(a.y) * (1.f / (1.f + __expf(-bf2f(g.y)))));
    o.z = f2bf(bf2f(a.z) * (1.f / (1.f + __expf(-bf2f(g.z)))));
    o.w = f2bf(bf2f(a.w) * (1.f / (1.f + __expf(-bf2f(g.w)))));
    *(bf16x4*)(out + j4) = o;
}

// row softmax over S=512; writes bf16 (next GEMM input) + optional f32 (final attention)
__global__ __launch_bounds__(256) void softmax_kernel(const float* __restrict__ energy,
                                                      float* __restrict__ attn_f32,
                                                      __hip_bfloat16* __restrict__ attn_bf) {
    int row = blockIdx.x;  // 0..8191
    const float* e = energy + (long)row * Sn;
    int tid = threadIdx.x;
    float v0 = e[tid], v1 = e[tid + 256];
    float m = fmaxf(v0, v1);
    for (int off = 32; off; off >>= 1) m = fmaxf(m, __shfl_xor(m, off));
    __shared__ float redm[4];
    __shared__ float reds[4];
    int lane = tid & 63, w = tid >> 6;
    if (lane == 0) redm[w] = m;
    __syncthreads();
    m = fmaxf(fmaxf(redm[0], redm[1]), fmaxf(redm[2], redm[3]));
    float x0 = __expf(v0 - m), x1 = __expf(v1 - m);
    float s = x0 + x1;
    for (int off = 32; off; off >>= 1) s += __shfl_xor(s, off);
    if (lane == 0) reds[w] = s;
    __syncthreads();
    s = reds[0] + reds[1] + reds[2] + reds[3];
    float inv = 1.f / s;
    long base = (long)row * Sn;
    if (attn_f32) {
        attn_f32[base + tid] = x0 * inv;
        attn_f32[base + tid + 256] = x1 * inv;
    }
    attn_bf[base + tid] = f2bf(x0 * inv);
    attn_bf[base + tid + 256] = f2bf(x1 * inv);
}

// ---------------- the MFMA GEMM (2-phase double-buffered pipeline) ----------------
// C[M,N] = A[M,K] @ B^T  where Bw is stored [N][K] bf16 (B-transposed / NT layout).
// 128x128 tile, BK=32, 4 waves, 4x4 mfma_f32_16x16x32_bf16 frags per wave.
// T3 minimum 2-phase recipe (§5.5): per iter {STAGE(buf^1, next) ; ds_read+MFMA on buf ;
// __syncthreads (= vmcnt(0)+lgkmcnt(0)+s_barrier)}. Load latency hides under MFMA.
// EPI: 0: x=acc+bias; 1: x=(acc+bias+R1)*s1; 2: x=((acc+bias+R1)*s1+R2)*s2
// IM2COL: A is conv_input [B*T][H]; virtual K=3*H with row shift m-2+tap, pad row for tau<0.
// NBOUND: guard B rows / C cols against N (fc_out N=10000).
template <int EPI, bool OUTF32, bool IM2COL, bool NBOUND>
__global__ __launch_bounds__(256) void gemm_bf16(
    const __hip_bfloat16* __restrict__ A, const __hip_bfloat16* __restrict__ Bw,
    const float* __restrict__ bias, void* __restrict__ Cout,
    const __hip_bfloat16* __restrict__ R1, const __hip_bfloat16* __restrict__ R2,
    const __hip_bfloat16* __restrict__ padrow,
    int M, int N, int K, long aZ, long bZ, long cZ, float s1, float s2) {
    __shared__ alignas(16) short As[2][128 * 32];
    __shared__ alignas(16) short Bs[2][128 * 32];
    const int tid = threadIdx.x;
    const int lane = tid & 63;
    const int wid = tid >> 6;
    const int wr = wid >> 1, wc = wid & 1;
    const int m0 = blockIdx.y * 128, n0 = blockIdx.x * 128;
    const short* Ag = (const short*)A + (long)blockIdx.z * aZ;
    const short* Bg = (const short*)Bw + (long)blockIdx.z * bZ;
    const short* pad = (const short*)padrow;

    f32x4 acc[4][4] = {};

    const int rc = tid >> 2;        // staging row (j=0); LDS byte off = tid*16 (linear)
    const int k8 = (tid & 3) * 8;   // element offset within the 32-wide row

    auto stage = [&](int buf, int k0) {
#pragma unroll
        for (int j = 0; j < 2; ++j) {
            int r = rc + j * 64;
            const short* asrc;
            if (IM2COL) {
                int m = m0 + r;
                int t = m & (Tn - 1);
                int tap = k0 >> 10;
                int tau = t - 2 + tap;
                int kcol = (k0 & (Hn - 1)) + k8;
                asrc = (tau >= 0) ? (Ag + (long)(m - 2 + tap) * Hn + kcol) : (pad + k8);
            } else {
                asrc = Ag + (long)(m0 + r) * K + k0 + k8;
            }
            gload_lds16(asrc, &As[buf][r * 32 + k8]);
            int n = n0 + r;
            const short* bsrc = (NBOUND && n >= N) ? (pad + k8) : (Bg + (long)n * K + k0 + k8);
            gload_lds16(bsrc, &Bs[buf][r * 32 + k8]);
        }
    };

    // prologue: stage tile 0; __syncthreads drains vmcnt(0) so tile 0 is visible
    stage(0, 0);
    __syncthreads();

    int cur = 0;
    for (int k0 = 0; k0 < K; k0 += 32) {
        if (k0 + 32 < K) stage(cur ^ 1, k0 + 32);   // issue next-tile loads (in flight over MFMA)
        const int rsel = lane & 15, hi = (lane >> 4) * 8;
        short8 af[4], bg[4];
#pragma unroll
        for (int mi = 0; mi < 4; ++mi)
            af[mi] = *(const short8*)&As[cur][(wr * 64 + mi * 16 + rsel) * 32 + hi];
#pragma unroll
        for (int ni = 0; ni < 4; ++ni)
            bg[ni] = *(const short8*)&Bs[cur][(wc * 64 + ni * 16 + rsel) * 32 + hi];
#pragma unroll
        for (int mi = 0; mi < 4; ++mi)
#pragma unroll
            for (int ni = 0; ni < 4; ++ni)
                acc[mi][ni] = __builtin_amdgcn_mfma_f32_16x16x32_bf16(af[mi], bg[ni], acc[mi][ni], 0, 0, 0);
        __syncthreads();  // vmcnt(0)+lgkmcnt(0)+barrier: next tile staged, reads of cur done
        cur ^= 1;
    }

    // epilogue: C/D layout col=lane&15, row=(lane>>4)*4+reg  [verified m89/m91]
    const int rsel = lane & 15, rg = (lane >> 4) * 4;
    float* Cf = (float*)Cout + (long)blockIdx.z * cZ;
    __hip_bfloat16* Cb = (__hip_bfloat16*)Cout + (long)blockIdx.z * cZ;
#pragma unroll
    for (int ni = 0; ni < 4; ++ni) {
        int col = n0 + wc * 64 + ni * 16 + rsel;
        if (NBOUND && col >= N) continue;
        float bi = bias ? bias[col] : 0.f;
#pragma unroll
        for (int mi = 0; mi < 4; ++mi) {
            int row = m0 + wr * 64 + mi * 16 + rg;
            f32x4 v = acc[mi][ni];
#pragma unroll
            for (int q = 0; q < 4; ++q) {
                long idx = (long)(row + q) * N + col;
                float x = v[q] + bi;
                if (EPI >= 1) x = (x + bf2f(R1[idx])) * s1;
                if (EPI >= 2) x = (x + bf2f(R2[idx])) * s2;
                if (OUTF32) Cf[idx] = x;
                else Cb[idx] = f2bf(x);
            }
        }
    }
}

// ---------------- launcher ----------------

extern "C" void kernel_launch(void* const* d_in, const int* in_sizes, int n_in,
                              void* d_out, int out_size, void* d_ws, size_t ws_size,
                              hipStream_t stream) {
    const int* tgt = (const int*)d_in[0];
    const float* enc_conved = (const float*)d_in[1];
    const float* enc_combined = (const float*)d_in[2];
    const float* tok_emb = (const float*)d_in[3];
    const float* pos_emb = (const float*)d_in[4];
    const float* w_e2h = (const float*)d_in[5];
    const float* b_e2h = (const float*)d_in[6];
    const float* w_h2e = (const float*)d_in[7];
    const float* b_h2e = (const float*)d_in[8];
    const float* w_ah2e = (const float*)d_in[9];
    const float* b_ah2e = (const float*)d_in[10];
    const float* w_ae2h = (const float*)d_in[11];
    const float* b_ae2h = (const float*)d_in[12];
    const float* w_fc = (const float*)d_in[13];
    const float* b_fc = (const float*)d_in[14];
    const float* conv_w = (const float*)d_in[15];
    const float* conv_b = (const float*)d_in[16];

    char* ws = (char*)d_ws;
    size_t off = 0;
    auto alloc = [&](size_t bytes) { size_t r = off; off = (off + bytes + 255) & ~(size_t)255; return r; };
    __hip_bfloat16* emb    = (__hip_bfloat16*)(ws + alloc((size_t)Mn * En * 2));        // 8.4 MB
    __hip_bfloat16* convin = (__hip_bfloat16*)(ws + alloc((size_t)Mn * Hn * 2));        // 16.8 MB
    size_t o_pre = alloc((size_t)Mn * 2 * Hn * 2);                                      // 33.6 MB
    __hip_bfloat16* pre = (__hip_bfloat16*)(ws + o_pre);
    float* energy = (float*)(ws + o_pre);                        // overlays pre (dead after GLU)
    __hip_bfloat16* attnbf = (__hip_bfloat16*)(ws + o_pre + (size_t)Mn * Sn * 4);
    __hip_bfloat16* conved = (__hip_bfloat16*)(ws + alloc((size_t)Mn * Hn * 2));        // 16.8 MB
    __hip_bfloat16* tmpE   = (__hip_bfloat16*)(ws + alloc((size_t)Mn * En * 2));        // 8.4 MB
    __hip_bfloat16* wT_e2h = (__hip_bfloat16*)(ws + alloc((size_t)Hn * En * 2));
    __hip_bfloat16* wT_h2e = (__hip_bfloat16*)(ws + alloc((size_t)En * Hn * 2));
    __hip_bfloat16* wT_ah2e= (__hip_bfloat16*)(ws + alloc((size_t)En * Hn * 2));
    __hip_bfloat16* wT_ae2h= (__hip_bfloat16*)(ws + alloc((size_t)Hn * En * 2));
    __hip_bfloat16* wT_fc  = (__hip_bfloat16*)(ws + alloc((size_t)Vn * En * 2));        // 10.2 MB
    __hip_bfloat16* wpack  = (__hip_bfloat16*)(ws + alloc((size_t)2 * Hn * 3 * Hn * 2));// 25.2 MB
    __hip_bfloat16* encc   = (__hip_bfloat16*)(ws + alloc((size_t)Bn * Sn * En * 2));   // 8.4 MB
    __hip_bfloat16* encTc  = (__hip_bfloat16*)(ws + alloc((size_t)Bn * En * Sn * 2));   // 8.4 MB
    __hip_bfloat16* padrow = (__hip_bfloat16*)(ws + alloc(256));

    float* out = (float*)d_out;
    float* attn_out = out + (long)Mn * Vn;
    const long bSq = (long)Sn * Sn;  // 262144, per-batch stride for T=S=E=512 blocks

    dim3 tb(32, 8);

    // ---- prep ----
    padfill_kernel<<<1, 128, 0, stream>>>(padrow);
    embed_kernel<<<Mn, 128, 0, stream>>>(tgt, tok_emb, pos_emb, emb);
    transpose_f32_bf16<<<dim3(Hn / 32, En / 32, 1), tb, 0, stream>>>(w_e2h, wT_e2h, En, Hn, 0, 0);
    transpose_f32_bf16<<<dim3(En / 32, Hn / 32, 1), tb, 0, stream>>>(w_h2e, wT_h2e, Hn, En, 0, 0);
    transpose_f32_bf16<<<dim3(En / 32, Hn / 32, 1), tb, 0, stream>>>(w_ah2e, wT_ah2e, Hn, En, 0, 0);
    transpose_f32_bf16<<<dim3(Hn / 32, En / 32, 1), tb, 0, stream>>>(w_ae2h, wT_ae2h, En, Hn, 0, 0);
    transpose_f32_bf16<<<dim3((Vn + 31) / 32, En / 32, 1), tb, 0, stream>>>(w_fc, wT_fc, En, Vn, 0, 0);
    transpose_f32_bf16<<<dim3(En / 32, Sn / 32, Bn), tb, 0, stream>>>(enc_combined, encTc, Sn, En, bSq, bSq);
    convert_bf16_kernel<<<((long)Bn * Sn * En / 4 + 255) / 256, 256, 0, stream>>>(enc_conved, encc, (long)Bn * Sn * En / 4);

    // conv_input = embedded @ emb2hid + b       [8192,1024]
    gemm_bf16<0, false, false, false><<<dim3(Hn / 128, Mn / 128, 1), 256, 0, stream>>>(
        emb, wT_e2h, b_e2h, convin, nullptr, nullptr, padrow, Mn, Hn, En, 0, 0, 0, 1.f, 1.f);

    for (int l = 0; l < Ln; ++l) {
        // pack conv weight for this layer (within-row permutation, f32->bf16)
        wpack_kernel<<<dim3(3 * Hn / 256, 2 * Hn, 1), 256, 0, stream>>>(conv_w, wpack, l);
        // pre = im2col(conv_input) @ wpack^T + conv_b[l]    [8192,2048], K=3072
        gemm_bf16<0, false, true, false><<<dim3(2 * Hn / 128, Mn / 128, 1), 256, 0, stream>>>(
            convin, wpack, conv_b + (long)l * 2 * Hn, pre, nullptr, nullptr, padrow,
            Mn, 2 * Hn, 3 * Hn, 0, 0, 0, 1.f, 1.f);
        // conved = GLU(pre)
        glu_kernel<<<(Mn * Hn / 4) / 256, 256, 0, stream>>>(pre, conved);
        // combined = (conved @ attn_hid2emb + b + embedded) * scale   [8192,512]
        gemm_bf16<1, false, false, false><<<dim3(En / 128, Mn / 128, 1), 256, 0, stream>>>(
            conved, wT_ah2e, b_ah2e, tmpE, emb, nullptr, padrow, Mn, En, Hn, 0, 0, 0, kScale, 1.f);
        // energy[b] = combined[b] @ enc_conved[b]^T   (batched NT, f32 out)
        gemm_bf16<0, true, false, false><<<dim3(Sn / 128, Tn / 128, Bn), 256, 0, stream>>>(
            tmpE, encc, nullptr, energy, nullptr, nullptr, padrow, Tn, Sn, En, bSq, bSq, bSq, 1.f, 1.f);
        // attention = softmax(energy)  (f32 out only needed from the LAST layer)
        softmax_kernel<<<Mn, 256, 0, stream>>>(energy, (l == Ln - 1) ? attn_out : nullptr, attnbf);
        // attended[b] = attention[b] @ enc_combined[b]   (batched, B pre-transposed)
        gemm_bf16<0, false, false, false><<<dim3(En / 128, Tn / 128, Bn), 256, 0, stream>>>(
            attnbf, encTc, nullptr, tmpE, nullptr, nullptr, padrow, Tn, En, Sn, bSq, bSq, bSq, 1.f, 1.f);
        // conv_input = ((attended @ attn_emb2hid + b + conved)*scale + conv_input)*scale
        gemm_bf16<2, false, false, false><<<dim3(Hn / 128, Mn / 128, 1), 256, 0, stream>>>(
            tmpE, wT_ae2h, b_ae2h, convin, conved, convin, padrow, Mn, Hn, En, 0, 0, 0, kScale, kScale);
    }

    // conved = conv_input @ hid2emb + b   [8192,512]
    gemm_bf16<0, false, false, false><<<dim3(En / 128, Mn / 128, 1), 256, 0, stream>>>(
        convin, wT_h2e, b_h2e, tmpE, nullptr, nullptr, padrow, Mn, En, Hn, 0, 0, 0, 1.f, 1.f);
    // output = conved @ fc_out + b        [8192,10000] f32, N-bounded
    gemm_bf16<0, true, false, true><<<dim3((Vn + 127) / 128, Mn / 128, 1), 256, 0, stream>>>(
        tmpE, wT_fc, b_fc, out, nullptr, nullptr, padrow, Mn, Vn, En, 0, 0, 0, 1.f, 1.f);
}

// Round 4
// 1643.330 us; speedup vs baseline: 1.2550x; 1.1597x over previous
//
#include <hip/hip_runtime.h>
#include <hip/hip_bf16.h>

typedef __attribute__((ext_vector_type(4))) float f32x4;
typedef __attribute__((ext_vector_type(8))) short short8;

#define DEVFN __device__ __forceinline__

static constexpr int Bn = 16, Tn = 512, Sn = 512, Vn = 10000, En = 512, Hn = 1024, Ln = 6;
static constexpr int Mn = Bn * Tn;  // 8192 token rows
static constexpr float kScale = 0.70710678118654752440f;

DEVFN float bf2f(__hip_bfloat16 x) { return __bfloat162float(x); }
DEVFN __hip_bfloat16 f2bf(float x) { return __float2bfloat16(x); }

struct bf16x4 { __hip_bfloat16 x, y, z, w; };

// async global -> LDS, 16B per lane (wave-uniform LDS base + lane*16 layout)
DEVFN void gload_lds16(const short* g, short* l) {
    __builtin_amdgcn_global_load_lds((const __attribute__((address_space(1))) void*)g,
                                     (__attribute__((address_space(3))) void*)l, 16, 0, 0);
}

// ---------------- small prep kernels ----------------

__global__ void padfill_kernel(__hip_bfloat16* p) {
    p[threadIdx.x] = f2bf(1.0f);  // PAD_VAL as float, per torch code
}

// embedded[b,t,:] = tok_emb[tgt[b,t],:] + pos_emb[t,:]   (bf16 out)
__global__ void embed_kernel(const int* __restrict__ tgt, const float* __restrict__ tok,
                             const float* __restrict__ pos, __hip_bfloat16* __restrict__ out) {
    int row = blockIdx.x;              // 0..8191
    int t = row & (Tn - 1);
    int v = tgt[row];
    const float* tr = tok + (long)v * En;
    const float* pr = pos + (long)t * En;
    __hip_bfloat16* orow = out + (long)row * En;
    int e = threadIdx.x * 4;           // block 128 covers 512
    float4 a = *(const float4*)(tr + e);
    float4 b = *(const float4*)(pr + e);
    bf16x4 o{f2bf(a.x + b.x), f2bf(a.y + b.y), f2bf(a.z + b.z), f2bf(a.w + b.w)};
    *(bf16x4*)(orow + e) = o;
}

// dst[c][r] = bf16(src[r][c]); src is [R][C] f32. grid(ceil(C/32), ceil(R/32), Z), block(32,8)
__global__ void transpose_f32_bf16(const float* __restrict__ src, __hip_bfloat16* __restrict__ dst,
                                   int R, int C, long sZi, long sZo) {
    __shared__ float tile[32][33];
    src += (long)blockIdx.z * sZi;
    dst += (long)blockIdx.z * sZo;
    int c0 = blockIdx.x * 32, r0 = blockIdx.y * 32;
    for (int i = threadIdx.y; i < 32; i += 8) {
        int r = r0 + i, c = c0 + threadIdx.x;
        tile[i][threadIdx.x] = (r < R && c < C) ? src[(long)r * C + c] : 0.f;
    }
    __syncthreads();
    for (int i = threadIdx.y; i < 32; i += 8) {
        int c = c0 + i, r = r0 + threadIdx.x;
        if (c < C && r < R) dst[(long)c * R + r] = f2bf(tile[threadIdx.x][i]);
    }
}

// plain f32 -> bf16 convert (n divisible by 4)
__global__ void convert_bf16_kernel(const float* __restrict__ src, __hip_bfloat16* __restrict__ dst, long n4) {
    long i = (long)blockIdx.x * blockDim.x + threadIdx.x;
    if (i >= n4) return;
    long j = i * 4;
    float4 v = *(const float4*)(src + j);
    bf16x4 o{f2bf(v.x), f2bf(v.y), f2bf(v.z), f2bf(v.w)};
    *(bf16x4*)(dst + j) = o;
}

// conv weight pack for layer l: wp[o][tap*H+i] = bf16(conv_w[l][o][i][tap])
__global__ void wpack_kernel(const float* __restrict__ convw, __hip_bfloat16* __restrict__ wp, int l) {
    int kk = blockIdx.x * 256 + threadIdx.x;  // 0..3071
    int o = blockIdx.y;                        // 0..2047
    int i = kk & (Hn - 1);
    int tap = kk >> 10;
    long base = ((long)(l * 2 * Hn + o)) * (Hn * 3);
    wp[(long)o * (3 * Hn) + kk] = f2bf(convw[base + (long)i * 3 + tap]);
}

// GLU: out[m][j] = pre[m][j] * sigmoid(pre[m][H+j]); 4 elems/thread
__global__ void glu_kernel(const __hip_bfloat16* __restrict__ pre, __hip_bfloat16* __restrict__ out) {
    long idx = (long)blockIdx.x * blockDim.x + threadIdx.x;
    long j4 = idx * 4;
    if (j4 >= (long)Mn * Hn) return;
    int m = (int)(j4 >> 10);
    int j = (int)(j4 & (Hn - 1));
    bf16x4 a = *(const bf16x4*)(pre + (long)m * 2 * Hn + j);
    bf16x4 g = *(const bf16x4*)(pre + (long)m * 2 * Hn + Hn + j);
    bf16x4 o;
    o.x = f2bf(bf2f(a.x) * (1.f / (1.f + __expf(-bf2f(g.x)))));
    o.y = f2bf(bf2f(a.y) * (1.f / (1.f + __expf(-bf2f(g.y)))));
    o.z = f2bf(bf2f(a.z) * (1.f / (1.f + __expf(-bf2f(g.z)))));
    o.w = f2bf(bf2f(a.w) * (1.f / (1.f + __expf(-bf2f(g.w)))));
    *(bf16x4*)(out + j4) = o;
}

// row softmax over S=512; writes bf16 (next GEMM input) + optional f32 (final attention)
__global__ __launch_bounds__(256) void softmax_kernel(const float* __restrict__ energy,
                                                      float* __restrict__ attn_f32,
                                                      __hip_bfloat16* __restrict__ attn_bf) {
    int row = blockIdx.x;  // 0..8191
    const float* e = energy + (long)row * Sn;
    int tid = threadIdx.x;
    float v0 = e[tid], v1 = e[tid + 256];
    float m = fmaxf(v0, v1);
    for (int off = 32; off; off >>= 1) m = fmaxf(m, __shfl_xor(m, off));
    __shared__ float redm[4];
    __shared__ float reds[4];
    int lane = tid & 63, w = tid >> 6;
    if (lane == 0) redm[w] = m;
    __syncthreads();
    m = fmaxf(fmaxf(redm[0], redm[1]), fmaxf(redm[2], redm[3]));
    float x0 = __expf(v0 - m), x1 = __expf(v1 - m);
    float s = x0 + x1;
    for (int off = 32; off; off >>= 1) s += __shfl_xor(s, off);
    if (lane == 0) reds[w] = s;
    __syncthreads();
    s = reds[0] + reds[1] + reds[2] + reds[3];
    float inv = 1.f / s;
    long base = (long)row * Sn;
    if (attn_f32) {
        attn_f32[base + tid] = x0 * inv;
        attn_f32[base + tid + 256] = x1 * inv;
    }
    attn_bf[base + tid] = f2bf(x0 * inv);
    attn_bf[base + tid + 256] = f2bf(x1 * inv);
}

// ---------------- 128x128 2-phase GEMM (small / batched ops) ----------------
template <int EPI, bool OUTF32, bool NBOUND>
__global__ __launch_bounds__(256) void gemm_bf16(
    const __hip_bfloat16* __restrict__ A, const __hip_bfloat16* __restrict__ Bw,
    const float* __restrict__ bias, void* __restrict__ Cout,
    const __hip_bfloat16* __restrict__ R1, const __hip_bfloat16* __restrict__ R2,
    const __hip_bfloat16* __restrict__ padrow,
    int M, int N, int K, long aZ, long bZ, long cZ, float s1, float s2) {
    __shared__ alignas(16) short As[2][128 * 32];
    __shared__ alignas(16) short Bs[2][128 * 32];
    const int tid = threadIdx.x;
    const int lane = tid & 63;
    const int wid = tid >> 6;
    const int wr = wid >> 1, wc = wid & 1;
    const int m0 = blockIdx.y * 128, n0 = blockIdx.x * 128;
    const short* Ag = (const short*)A + (long)blockIdx.z * aZ;
    const short* Bg = (const short*)Bw + (long)blockIdx.z * bZ;
    const short* pad = (const short*)padrow;

    f32x4 acc[4][4] = {};

    const int rc = tid >> 2;        // staging row (j=0); LDS byte off = tid*16 (linear)
    const int k8 = (tid & 3) * 8;   // element offset within the 32-wide row

    auto stage = [&](int buf, int k0) {
#pragma unroll
        for (int j = 0; j < 2; ++j) {
            int r = rc + j * 64;
            const short* asrc = Ag + (long)(m0 + r) * K + k0 + k8;
            gload_lds16(asrc, &As[buf][r * 32 + k8]);
            int n = n0 + r;
            const short* bsrc = (NBOUND && n >= N) ? (pad + k8) : (Bg + (long)n * K + k0 + k8);
            gload_lds16(bsrc, &Bs[buf][r * 32 + k8]);
        }
    };

    stage(0, 0);
    __syncthreads();

    int cur = 0;
    for (int k0 = 0; k0 < K; k0 += 32) {
        if (k0 + 32 < K) stage(cur ^ 1, k0 + 32);   // issue next-tile loads (in flight over MFMA)
        const int rsel = lane & 15, hi = (lane >> 4) * 8;
        short8 af[4], bg[4];
#pragma unroll
        for (int mi = 0; mi < 4; ++mi)
            af[mi] = *(const short8*)&As[cur][(wr * 64 + mi * 16 + rsel) * 32 + hi];
#pragma unroll
        for (int ni = 0; ni < 4; ++ni)
            bg[ni] = *(const short8*)&Bs[cur][(wc * 64 + ni * 16 + rsel) * 32 + hi];
#pragma unroll
        for (int mi = 0; mi < 4; ++mi)
#pragma unroll
            for (int ni = 0; ni < 4; ++ni)
                acc[mi][ni] = __builtin_amdgcn_mfma_f32_16x16x32_bf16(af[mi], bg[ni], acc[mi][ni], 0, 0, 0);
        __syncthreads();  // vmcnt(0)+lgkmcnt(0)+barrier: next tile staged, reads of cur done
        cur ^= 1;
    }

    const int rsel = lane & 15, rg = (lane >> 4) * 4;
    float* Cf = (float*)Cout + (long)blockIdx.z * cZ;
    __hip_bfloat16* Cb = (__hip_bfloat16*)Cout + (long)blockIdx.z * cZ;
#pragma unroll
    for (int ni = 0; ni < 4; ++ni) {
        int col = n0 + wc * 64 + ni * 16 + rsel;
        if (NBOUND && col >= N) continue;
        float bi = bias ? bias[col] : 0.f;
#pragma unroll
        for (int mi = 0; mi < 4; ++mi) {
            int row = m0 + wr * 64 + mi * 16 + rg;
            f32x4 v = acc[mi][ni];
#pragma unroll
            for (int q = 0; q < 4; ++q) {
                long idx = (long)(row + q) * N + col;
                float x = v[q] + bi;
                if (EPI >= 1) x = (x + bf2f(R1[idx])) * s1;
                if (EPI >= 2) x = (x + bf2f(R2[idx])) * s2;
                if (OUTF32) Cf[idx] = x;
                else Cb[idx] = f2bf(x);
            }
        }
    }
}

// ---------------- 256x256 deep-pipeline GEMM (conv + fc_out) ----------------
// T1 XCD-swizzle + T2 LDS-swizzle (both-sides involution, rule #21) + T3/T4 counted
// vmcnt(8) double-buffer + T5 setprio. 8 waves (2Mx4N), BK=64, 4 quadrant-phases/tile
// of {12 ds_read_b128 ; 16 MFMA}. LDS 128 KiB -> 1 block/CU, 2 waves/SIMD.
// Swizzle: LDS slot (row, cs) holds logical (row, cs ^ ((row&7)<<3)); staging fetches
// global col ((tid&7)^(row&7))*8 into linear dst j*4096 + tid*8 (DMA wave-linear ✓).
template <bool OUTF32, bool IM2COL, bool NBOUND>
__global__ __launch_bounds__(512, 2) void gemm256(
    const __hip_bfloat16* __restrict__ A, const __hip_bfloat16* __restrict__ Bw,
    const float* __restrict__ bias, void* __restrict__ Cout,
    const __hip_bfloat16* __restrict__ padrow, int M, int N, int K) {
    __shared__ alignas(16) short As[2][256 * 64];
    __shared__ alignas(16) short Bs[2][256 * 64];
    const int tid = threadIdx.x;
    const int lane = tid & 63;
    const int wid = tid >> 6;
    const int wr = wid >> 2, wc = wid & 3;
    // T1: bijective XCD swizzle (m204) on the linearized block id
    const int nwg = gridDim.x * gridDim.y;
    const int orig = blockIdx.y * gridDim.x + blockIdx.x;
    const int qd = nwg >> 3, rd = nwg & 7, xc = orig & 7, loc = orig >> 3;
    const int bid = (xc < rd ? xc * (qd + 1) : rd * (qd + 1) + (xc - rd) * qd) + loc;
    const int n0 = (bid % gridDim.x) * 256, m0 = (bid / gridDim.x) * 256;
    const short* Ag = (const short*)A;
    const short* Bg = (const short*)Bw;
    const short* pad = (const short*)padrow;

    f32x4 acc[8][4] = {};

    const int srow_l = tid >> 3;        // staging row low bits (j*64 + srow_l)
    const int scol = ((tid & 7) ^ (srow_l & 7)) * 8;  // inverse-swizzled global col (shorts)
    const int sdst = (tid >> 3) * 64 + (tid & 7) * 8; // linear LDS dst = tid*8 elems

    auto stage = [&](int buf, int kt) {
        const int k0 = kt * 64;
#pragma unroll
        for (int j = 0; j < 4; ++j) {
            const int row = j * 64 + srow_l;
            const short* asrc;
            if (IM2COL) {
                int m = m0 + row;
                int t = m & (Tn - 1);
                int tap = k0 >> 10;                 // uniform per K-tile (1024 % 64 == 0)
                int tau = t - 2 + tap;
                int kcol = (k0 & (Hn - 1)) + scol;
                asrc = (tau >= 0) ? (Ag + (long)(m - 2 + tap) * Hn + kcol) : (pad + scol);
            } else {
                asrc = Ag + (long)(m0 + row) * K + k0 + scol;
            }
            gload_lds16(asrc, &As[buf][j * 4096 + sdst]);
            int n = n0 + row;
            const short* bsrc = (NBOUND && n >= N) ? (pad + scol) : (Bg + (long)n * K + k0 + scol);
            gload_lds16(bsrc, &Bs[buf][j * 4096 + sdst]);
        }
    };

    const int rsel = lane & 15, hi = (lane >> 4) * 8;
    const int xorc = (rsel & 7) << 3;   // read-side swizzle (row&7 == rsel&7 for all frags)

    stage(0, 0);
    const int NT = K >> 6;
    for (int t = 0; t < NT; ++t) {
        const int cur = t & 1;
        if (t + 1 < NT) {
            stage(cur ^ 1, t + 1);                    // 8 loads for tile t+1, stay in flight
            asm volatile("s_waitcnt vmcnt(8)" ::: "memory");   // tile t's 8 loads done
        } else {
            asm volatile("s_waitcnt vmcnt(0)" ::: "memory");
        }
        __builtin_amdgcn_s_barrier();                 // all threads' tile-t DMA visible
        __builtin_amdgcn_sched_barrier(0);
#pragma unroll
        for (int ph = 0; ph < 4; ++ph) {              // quadrant phases: mh in M, nh in N
            const int mh = ph >> 1, nh = ph & 1;
            short8 af[4][2], bg[2][2];
#pragma unroll
            for (int i = 0; i < 4; ++i) {
                const int row = wr * 128 + mh * 64 + i * 16 + rsel;
#pragma unroll
                for (int ks = 0; ks < 2; ++ks)
                    af[i][ks] = *(const short8*)&As[cur][row * 64 + ((ks * 32 + hi) ^ xorc)];
            }
#pragma unroll
            for (int i = 0; i < 2; ++i) {
                const int row = wc * 64 + nh * 32 + i * 16 + rsel;
#pragma unroll
                for (int ks = 0; ks < 2; ++ks)
                    bg[i][ks] = *(const short8*)&Bs[cur][row * 64 + ((ks * 32 + hi) ^ xorc)];
            }
            __builtin_amdgcn_s_setprio(1);
#pragma unroll
            for (int i = 0; i < 4; ++i)
#pragma unroll
                for (int jn = 0; jn < 2; ++jn)
#pragma unroll
                    for (int ks = 0; ks < 2; ++ks)
                        acc[mh * 4 + i][nh * 2 + jn] = __builtin_amdgcn_mfma_f32_16x16x32_bf16(
                            af[i][ks], bg[jn][ks], acc[mh * 4 + i][nh * 2 + jn], 0, 0, 0);
            __builtin_amdgcn_s_setprio(0);
            __builtin_amdgcn_sched_barrier(0);        // pin phase boundaries
        }
        __builtin_amdgcn_s_barrier();                 // all reads of cur done before reuse
        __builtin_amdgcn_sched_barrier(0);
    }

    const int rg = (lane >> 4) * 4;
    float* Cf = (float*)Cout;
    __hip_bfloat16* Cb = (__hip_bfloat16*)Cout;
#pragma unroll
    for (int ni = 0; ni < 4; ++ni) {
        int col = n0 + wc * 64 + ni * 16 + rsel;
        if (NBOUND && col >= N) continue;
        float bi = bias ? bias[col] : 0.f;
#pragma unroll
        for (int mi = 0; mi < 8; ++mi) {
            int row = m0 + wr * 128 + mi * 16 + rg;
            f32x4 v = acc[mi][ni];
#pragma unroll
            for (int q = 0; q < 4; ++q) {
                long idx = (long)(row + q) * N + col;
                float x = v[q] + bi;
                if (OUTF32) Cf[idx] = x;
                else Cb[idx] = f2bf(x);
            }
        }
    }
}

// ---------------- launcher ----------------

extern "C" void kernel_launch(void* const* d_in, const int* in_sizes, int n_in,
                              void* d_out, int out_size, void* d_ws, size_t ws_size,
                              hipStream_t stream) {
    const int* tgt = (const int*)d_in[0];
    const float* enc_conved = (const float*)d_in[1];
    const float* enc_combined = (const float*)d_in[2];
    const float* tok_emb = (const float*)d_in[3];
    const float* pos_emb = (const float*)d_in[4];
    const float* w_e2h = (const float*)d_in[5];
    const float* b_e2h = (const float*)d_in[6];
    const float* w_h2e = (const float*)d_in[7];
    const float* b_h2e = (const float*)d_in[8];
    const float* w_ah2e = (const float*)d_in[9];
    const float* b_ah2e = (const float*)d_in[10];
    const float* w_ae2h = (const float*)d_in[11];
    const float* b_ae2h = (const float*)d_in[12];
    const float* w_fc = (const float*)d_in[13];
    const float* b_fc = (const float*)d_in[14];
    const float* conv_w = (const float*)d_in[15];
    const float* conv_b = (const float*)d_in[16];

    char* ws = (char*)d_ws;
    size_t off = 0;
    auto alloc = [&](size_t bytes) { size_t r = off; off = (off + bytes + 255) & ~(size_t)255; return r; };
    __hip_bfloat16* emb    = (__hip_bfloat16*)(ws + alloc((size_t)Mn * En * 2));        // 8.4 MB
    __hip_bfloat16* convin = (__hip_bfloat16*)(ws + alloc((size_t)Mn * Hn * 2));        // 16.8 MB
    size_t o_pre = alloc((size_t)Mn * 2 * Hn * 2);                                      // 33.6 MB
    __hip_bfloat16* pre = (__hip_bfloat16*)(ws + o_pre);
    float* energy = (float*)(ws + o_pre);                        // overlays pre (dead after GLU)
    __hip_bfloat16* attnbf = (__hip_bfloat16*)(ws + o_pre + (size_t)Mn * Sn * 4);
    __hip_bfloat16* conved = (__hip_bfloat16*)(ws + alloc((size_t)Mn * Hn * 2));        // 16.8 MB
    __hip_bfloat16* tmpE   = (__hip_bfloat16*)(ws + alloc((size_t)Mn * En * 2));        // 8.4 MB
    __hip_bfloat16* wT_e2h = (__hip_bfloat16*)(ws + alloc((size_t)Hn * En * 2));
    __hip_bfloat16* wT_h2e = (__hip_bfloat16*)(ws + alloc((size_t)En * Hn * 2));
    __hip_bfloat16* wT_ah2e= (__hip_bfloat16*)(ws + alloc((size_t)En * Hn * 2));
    __hip_bfloat16* wT_ae2h= (__hip_bfloat16*)(ws + alloc((size_t)Hn * En * 2));
    __hip_bfloat16* wT_fc  = (__hip_bfloat16*)(ws + alloc((size_t)Vn * En * 2));        // 10.2 MB
    __hip_bfloat16* wpack  = (__hip_bfloat16*)(ws + alloc((size_t)2 * Hn * 3 * Hn * 2));// 25.2 MB
    __hip_bfloat16* encc   = (__hip_bfloat16*)(ws + alloc((size_t)Bn * Sn * En * 2));   // 8.4 MB
    __hip_bfloat16* encTc  = (__hip_bfloat16*)(ws + alloc((size_t)Bn * En * Sn * 2));   // 8.4 MB
    __hip_bfloat16* padrow = (__hip_bfloat16*)(ws + alloc(256));

    float* out = (float*)d_out;
    float* attn_out = out + (long)Mn * Vn;
    const long bSq = (long)Sn * Sn;  // 262144, per-batch stride for T=S=E=512 blocks

    dim3 tb(32, 8);

    // ---- prep ----
    padfill_kernel<<<1, 128, 0, stream>>>(padrow);
    embed_kernel<<<Mn, 128, 0, stream>>>(tgt, tok_emb, pos_emb, emb);
    transpose_f32_bf16<<<dim3(Hn / 32, En / 32, 1), tb, 0, stream>>>(w_e2h, wT_e2h, En, Hn, 0, 0);
    transpose_f32_bf16<<<dim3(En / 32, Hn / 32, 1), tb, 0, stream>>>(w_h2e, wT_h2e, Hn, En, 0, 0);
    transpose_f32_bf16<<<dim3(En / 32, Hn / 32, 1), tb, 0, stream>>>(w_ah2e, wT_ah2e, Hn, En, 0, 0);
    transpose_f32_bf16<<<dim3(Hn / 32, En / 32, 1), tb, 0, stream>>>(w_ae2h, wT_ae2h, En, Hn, 0, 0);
    transpose_f32_bf16<<<dim3((Vn + 31) / 32, En / 32, 1), tb, 0, stream>>>(w_fc, wT_fc, En, Vn, 0, 0);
    transpose_f32_bf16<<<dim3(En / 32, Sn / 32, Bn), tb, 0, stream>>>(enc_combined, encTc, Sn, En, bSq, bSq);
    convert_bf16_kernel<<<((long)Bn * Sn * En / 4 + 255) / 256, 256, 0, stream>>>(enc_conved, encc, (long)Bn * Sn * En / 4);

    // conv_input = embedded @ emb2hid + b       [8192,1024]
    gemm_bf16<0, false, false><<<dim3(Hn / 128, Mn / 128, 1), 256, 0, stream>>>(
        emb, wT_e2h, b_e2h, convin, nullptr, nullptr, padrow, Mn, Hn, En, 0, 0, 0, 1.f, 1.f);

    for (int l = 0; l < Ln; ++l) {
        // pack conv weight for this layer (within-row permutation, f32->bf16)
        wpack_kernel<<<dim3(3 * Hn / 256, 2 * Hn, 1), 256, 0, stream>>>(conv_w, wpack, l);
        // pre = im2col(conv_input) @ wpack^T + conv_b[l]    [8192,2048], K=3072  (256² pipeline)
        gemm256<false, true, false><<<dim3(2 * Hn / 256, Mn / 256, 1), 512, 0, stream>>>(
            convin, wpack, conv_b + (long)l * 2 * Hn, pre, padrow, Mn, 2 * Hn, 3 * Hn);
        // conved = GLU(pre)
        glu_kernel<<<(Mn * Hn / 4) / 256, 256, 0, stream>>>(pre, conved);
        // combined = (conved @ attn_hid2emb + b + embedded) * scale   [8192,512]
        gemm_bf16<1, false, false><<<dim3(En / 128, Mn / 128, 1), 256, 0, stream>>>(
            conved, wT_ah2e, b_ah2e, tmpE, emb, nullptr, padrow, Mn, En, Hn, 0, 0, 0, kScale, 1.f);
        // energy[b] = combined[b] @ enc_conved[b]^T   (batched NT, f32 out)
        gemm_bf16<0, true, false><<<dim3(Sn / 128, Tn / 128, Bn), 256, 0, stream>>>(
            tmpE, encc, nullptr, energy, nullptr, nullptr, padrow, Tn, Sn, En, bSq, bSq, bSq, 1.f, 1.f);
        // attention = softmax(energy)  (f32 out only needed from the LAST layer)
        softmax_kernel<<<Mn, 256, 0, stream>>>(energy, (l == Ln - 1) ? attn_out : nullptr, attnbf);
        // attended[b] = attention[b] @ enc_combined[b]   (batched, B pre-transposed)
        gemm_bf16<0, false, false><<<dim3(En / 128, Tn / 128, Bn), 256, 0, stream>>>(
            attnbf, encTc, nullptr, tmpE, nullptr, nullptr, padrow, Tn, En, Sn, bSq, bSq, bSq, 1.f, 1.f);
        // conv_input = ((attended @ attn_emb2hid + b + conved)*scale + conv_input)*scale
        gemm_bf16<2, false, false><<<dim3(Hn / 128, Mn / 128, 1), 256, 0, stream>>>(
            tmpE, wT_ae2h, b_ae2h, convin, conved, convin, padrow, Mn, Hn, En, 0, 0, 0, kScale, kScale);
    }

    // conved = conv_input @ hid2emb + b   [8192,512]
    gemm_bf16<0, false, false><<<dim3(En / 128, Mn / 128, 1), 256, 0, stream>>>(
        convin, wT_h2e, b_h2e, tmpE, nullptr, nullptr, padrow, Mn, En, Hn, 0, 0, 0, 1.f, 1.f);
    // output = conved @ fc_out + b        [8192,10000] f32, N-bounded  (256² pipeline)
    gemm256<true, false, true><<<dim3((Vn + 255) / 256, Mn / 256, 1), 512, 0, stream>>>(
        tmpE, wT_fc, b_fc, out, padrow, Mn, Vn, En);
}

// Round 5
// 1412.602 us; speedup vs baseline: 1.4599x; 1.1633x over previous
//
#include <hip/hip_runtime.h>
#include <hip/hip_bf16.h>

typedef __attribute__((ext_vector_type(4))) float f32x4;
typedef __attribute__((ext_vector_type(8))) short short8;

#define DEVFN __device__ __forceinline__

static constexpr int Bn = 16, Tn = 512, Sn = 512, Vn = 10000, En = 512, Hn = 1024, Ln = 6;
static constexpr int Mn = Bn * Tn;  // 8192 token rows
static constexpr float kScale = 0.70710678118654752440f;

DEVFN float bf2f(__hip_bfloat16 x) { return __bfloat162float(x); }
DEVFN __hip_bfloat16 f2bf(float x) { return __float2bfloat16(x); }

struct bf16x4 { __hip_bfloat16 x, y, z, w; };

// async global -> LDS, 16B per lane (wave-uniform LDS base + lane*16 layout)
DEVFN void gload_lds16(const short* g, short* l) {
    __builtin_amdgcn_global_load_lds((const __attribute__((address_space(1))) void*)g,
                                     (__attribute__((address_space(3))) void*)l, 16, 0, 0);
}

// ---------------- small prep kernels ----------------

__global__ void padfill_kernel(__hip_bfloat16* p) {
    p[threadIdx.x] = f2bf(1.0f);  // PAD_VAL as float, per torch code
}

// embedded[b,t,:] = tok_emb[tgt[b,t],:] + pos_emb[t,:]  (bf16)
// embA = kScale*(embedded + b_ah2e)                      (bf16, for embE precompute)
__global__ void embed_kernel(const int* __restrict__ tgt, const float* __restrict__ tok,
                             const float* __restrict__ pos, const float* __restrict__ bah,
                             __hip_bfloat16* __restrict__ out, __hip_bfloat16* __restrict__ outA) {
    int row = blockIdx.x;              // 0..8191
    int t = row & (Tn - 1);
    int v = tgt[row];
    const float* tr = tok + (long)v * En;
    const float* pr = pos + (long)t * En;
    int e = threadIdx.x * 4;           // block 128 covers 512
    float4 a = *(const float4*)(tr + e);
    float4 b = *(const float4*)(pr + e);
    float4 bb = *(const float4*)(bah + e);
    bf16x4 o{f2bf(a.x + b.x), f2bf(a.y + b.y), f2bf(a.z + b.z), f2bf(a.w + b.w)};
    *(bf16x4*)(out + (long)row * En + e) = o;
    bf16x4 oa{f2bf(kScale * (a.x + b.x + bb.x)), f2bf(kScale * (a.y + b.y + bb.y)),
              f2bf(kScale * (a.z + b.z + bb.z)), f2bf(kScale * (a.w + b.w + bb.w))};
    *(bf16x4*)(outA + (long)row * En + e) = oa;
}

// dst[c][r] = bf16(src[r][c]); src is [R][C] f32. grid(ceil(C/32), ceil(R/32), Z), block(32,8)
__global__ void transpose_f32_bf16(const float* __restrict__ src, __hip_bfloat16* __restrict__ dst,
                                   int R, int C, long sZi, long sZo) {
    __shared__ float tile[32][33];
    src += (long)blockIdx.z * sZi;
    dst += (long)blockIdx.z * sZo;
    int c0 = blockIdx.x * 32, r0 = blockIdx.y * 32;
    for (int i = threadIdx.y; i < 32; i += 8) {
        int r = r0 + i, c = c0 + threadIdx.x;
        tile[i][threadIdx.x] = (r < R && c < C) ? src[(long)r * C + c] : 0.f;
    }
    __syncthreads();
    for (int i = threadIdx.y; i < 32; i += 8) {
        int c = c0 + i, r = r0 + threadIdx.x;
        if (c < C && r < R) dst[(long)c * R + r] = f2bf(tile[threadIdx.x][i]);
    }
}

// plain f32 -> bf16 convert (n divisible by 4)
__global__ void convert_bf16_kernel(const float* __restrict__ src, __hip_bfloat16* __restrict__ dst, long n4) {
    long i = (long)blockIdx.x * blockDim.x + threadIdx.x;
    if (i >= n4) return;
    long j = i * 4;
    float4 v = *(const float4*)(src + j);
    bf16x4 o{f2bf(v.x), f2bf(v.y), f2bf(v.z), f2bf(v.w)};
    *(bf16x4*)(dst + j) = o;
}

// conv weight pack for layer l, a/g interleaved in 16-col blocks for fused GLU:
// packed col c: grp=c>>5, w=c&31; o = w<16 ? grp*16+w : H + grp*16 + (w-16)
// wp[c][tap*H+i] = bf16(conv_w[l][o][i][tap]).  grid(12, 2048), block 256.
__global__ void wpack_kernel(const float* __restrict__ convw, __hip_bfloat16* __restrict__ wp, int l) {
    int kk = blockIdx.x * 256 + threadIdx.x;  // 0..3071
    int c = blockIdx.y;                        // 0..2047 packed col
    int grp = c >> 5, w = c & 31;
    int o = (w < 16) ? grp * 16 + w : Hn + grp * 16 + (w - 16);
    int i = kk & (Hn - 1);
    int tap = kk >> 10;
    long base = ((long)(l * 2 * Hn + o)) * (Hn * 3);
    wp[(long)c * (3 * Hn) + kk] = f2bf(convw[base + (long)i * 3 + tap]);
}

// row softmax over S=512; writes bf16 (next GEMM input) + optional f32 (final attention)
__global__ __launch_bounds__(256) void softmax_kernel(const float* __restrict__ energy,
                                                      float* __restrict__ attn_f32,
                                                      __hip_bfloat16* __restrict__ attn_bf) {
    int row = blockIdx.x;  // 0..8191
    const float* e = energy + (long)row * Sn;
    int tid = threadIdx.x;
    float v0 = e[tid], v1 = e[tid + 256];
    float m = fmaxf(v0, v1);
    for (int off = 32; off; off >>= 1) m = fmaxf(m, __shfl_xor(m, off));
    __shared__ float redm[4];
    __shared__ float reds[4];
    int lane = tid & 63, w = tid >> 6;
    if (lane == 0) redm[w] = m;
    __syncthreads();
    m = fmaxf(fmaxf(redm[0], redm[1]), fmaxf(redm[2], redm[3]));
    float x0 = __expf(v0 - m), x1 = __expf(v1 - m);
    float s = x0 + x1;
    for (int off = 32; off; off >>= 1) s += __shfl_xor(s, off);
    if (lane == 0) reds[w] = s;
    __syncthreads();
    s = reds[0] + reds[1] + reds[2] + reds[3];
    float inv = 1.f / s;
    long base = (long)row * Sn;
    if (attn_f32) {
        attn_f32[base + tid] = x0 * inv;
        attn_f32[base + tid + 256] = x1 * inv;
    }
    attn_bf[base + tid] = f2bf(x0 * inv);
    attn_bf[base + tid + 256] = f2bf(x1 * inv);
}

// ---------------- 128x128 2-phase GEMM ----------------
// C[M,N] = A[M,K] @ Bw[N,K]^T.  EPI: 0: x=acc+bias; 2: x=((acc+bias+R1)*s1+R2)*s2;
// 3: x=acc*s1 + R1f[idx].  R1/R2/R1f batch-offset by z*cZ.
template <int EPI, bool OUTF32, bool NBOUND>
__global__ __launch_bounds__(256) void gemm_bf16(
    const __hip_bfloat16* __restrict__ A, const __hip_bfloat16* __restrict__ Bw,
    const float* __restrict__ bias, void* __restrict__ Cout,
    const __hip_bfloat16* __restrict__ R1, const __hip_bfloat16* __restrict__ R2,
    const float* __restrict__ R1f, const __hip_bfloat16* __restrict__ padrow,
    int M, int N, int K, long aZ, long bZ, long cZ, float s1, float s2) {
    __shared__ alignas(16) short As[2][128 * 32];
    __shared__ alignas(16) short Bs[2][128 * 32];
    const int tid = threadIdx.x;
    const int lane = tid & 63;
    const int wid = tid >> 6;
    const int wr = wid >> 1, wc = wid & 1;
    const int m0 = blockIdx.y * 128, n0 = blockIdx.x * 128;
    const short* Ag = (const short*)A + (long)blockIdx.z * aZ;
    const short* Bg = (const short*)Bw + (long)blockIdx.z * bZ;
    const short* pad = (const short*)padrow;

    f32x4 acc[4][4] = {};

    const int rc = tid >> 2;        // staging row (j=0); LDS byte off = tid*16 (linear)
    const int k8 = (tid & 3) * 8;   // element offset within the 32-wide row

    auto stage = [&](int buf, int k0) {
#pragma unroll
        for (int j = 0; j < 2; ++j) {
            int r = rc + j * 64;
            const short* asrc = Ag + (long)(m0 + r) * K + k0 + k8;
            gload_lds16(asrc, &As[buf][r * 32 + k8]);
            int n = n0 + r;
            const short* bsrc = (NBOUND && n >= N) ? (pad + k8) : (Bg + (long)n * K + k0 + k8);
            gload_lds16(bsrc, &Bs[buf][r * 32 + k8]);
        }
    };

    stage(0, 0);
    __syncthreads();

    int cur = 0;
    for (int k0 = 0; k0 < K; k0 += 32) {
        if (k0 + 32 < K) stage(cur ^ 1, k0 + 32);   // issue next-tile loads (in flight over MFMA)
        const int rsel = lane & 15, hi = (lane >> 4) * 8;
        short8 af[4], bg[4];
#pragma unroll
        for (int mi = 0; mi < 4; ++mi)
            af[mi] = *(const short8*)&As[cur][(wr * 64 + mi * 16 + rsel) * 32 + hi];
#pragma unroll
        for (int ni = 0; ni < 4; ++ni)
            bg[ni] = *(const short8*)&Bs[cur][(wc * 64 + ni * 16 + rsel) * 32 + hi];
#pragma unroll
        for (int mi = 0; mi < 4; ++mi)
#pragma unroll
            for (int ni = 0; ni < 4; ++ni)
                acc[mi][ni] = __builtin_amdgcn_mfma_f32_16x16x32_bf16(af[mi], bg[ni], acc[mi][ni], 0, 0, 0);
        __syncthreads();  // vmcnt(0)+lgkmcnt(0)+barrier: next tile staged, reads of cur done
        cur ^= 1;
    }

    const int rsel = lane & 15, rg = (lane >> 4) * 4;
    float* Cf = (float*)Cout + (long)blockIdx.z * cZ;
    __hip_bfloat16* Cb = (__hip_bfloat16*)Cout + (long)blockIdx.z * cZ;
    const __hip_bfloat16* R1z = R1 + (long)blockIdx.z * cZ;
    const __hip_bfloat16* R2z = R2 + (long)blockIdx.z * cZ;
    const float* R1fz = R1f + (long)blockIdx.z * cZ;
#pragma unroll
    for (int ni = 0; ni < 4; ++ni) {
        int col = n0 + wc * 64 + ni * 16 + rsel;
        if (NBOUND && col >= N) continue;
        float bi = (EPI != 3 && bias) ? bias[col] : 0.f;
#pragma unroll
        for (int mi = 0; mi < 4; ++mi) {
            int row = m0 + wr * 64 + mi * 16 + rg;
            f32x4 v = acc[mi][ni];
#pragma unroll
            for (int q = 0; q < 4; ++q) {
                long idx = (long)(row + q) * N + col;
                float x;
                if (EPI == 3) x = v[q] * s1 + R1fz[idx];
                else {
                    x = v[q] + bi;
                    if (EPI >= 1) x = (x + bf2f(R1z[idx])) * s1;
                    if (EPI >= 2) x = (x + bf2f(R2z[idx])) * s2;
                }
                if (OUTF32) Cf[idx] = x;
                else Cb[idx] = f2bf(x);
            }
        }
    }
}

// ---------------- 256x256 deep-pipeline GEMM (conv + fc_out) ----------------
// T1 XCD-swizzle + T2 LDS-swizzle (both-sides involution) + T3/T4 counted vmcnt(8)
// double-buffer + T5 setprio. 8 waves (2Mx4N), BK=64, 4 quadrant-phases/tile.
// GLUE: a/g channel pairs interleaved in 16-col blocks (wpack); epilogue computes
// (a+ba)*sigmoid(g+bg) and writes [M][N/2] bf16.
template <bool OUTF32, bool GLUE, bool IM2COL, bool NBOUND>
__global__ __launch_bounds__(512, 2) void gemm256(
    const __hip_bfloat16* __restrict__ A, const __hip_bfloat16* __restrict__ Bw,
    const float* __restrict__ bias, void* __restrict__ Cout,
    const __hip_bfloat16* __restrict__ padrow, int M, int N, int K) {
    __shared__ alignas(16) short As[2][256 * 64];
    __shared__ alignas(16) short Bs[2][256 * 64];
    const int tid = threadIdx.x;
    const int lane = tid & 63;
    const int wid = tid >> 6;
    const int wr = wid >> 2, wc = wid & 3;
    // T1: bijective XCD swizzle (m204) on the linearized block id
    const int nwg = gridDim.x * gridDim.y;
    const int orig = blockIdx.y * gridDim.x + blockIdx.x;
    const int qd = nwg >> 3, rd = nwg & 7, xc = orig & 7, loc = orig >> 3;
    const int bid = (xc < rd ? xc * (qd + 1) : rd * (qd + 1) + (xc - rd) * qd) + loc;
    const int n0 = (bid % gridDim.x) * 256, m0 = (bid / gridDim.x) * 256;
    const short* Ag = (const short*)A;
    const short* Bg = (const short*)Bw;
    const short* pad = (const short*)padrow;

    f32x4 acc[8][4] = {};

    const int srow_l = tid >> 3;        // staging row low bits (j*64 + srow_l)
    const int scol = ((tid & 7) ^ (srow_l & 7)) * 8;  // inverse-swizzled global col (shorts)
    const int sdst = (tid >> 3) * 64 + (tid & 7) * 8; // linear LDS dst = tid*8 elems

    auto stage = [&](int buf, int kt) {
        const int k0 = kt * 64;
#pragma unroll
        for (int j = 0; j < 4; ++j) {
            const int row = j * 64 + srow_l;
            const short* asrc;
            if (IM2COL) {
                int m = m0 + row;
                int t = m & (Tn - 1);
                int tap = k0 >> 10;                 // uniform per K-tile (1024 % 64 == 0)
                int tau = t - 2 + tap;
                int kcol = (k0 & (Hn - 1)) + scol;
                asrc = (tau >= 0) ? (Ag + (long)(m - 2 + tap) * Hn + kcol) : (pad + scol);
            } else {
                asrc = Ag + (long)(m0 + row) * K + k0 + scol;
            }
            gload_lds16(asrc, &As[buf][j * 4096 + sdst]);
            int n = n0 + row;
            const short* bsrc = (NBOUND && n >= N) ? (pad + scol) : (Bg + (long)n * K + k0 + scol);
            gload_lds16(bsrc, &Bs[buf][j * 4096 + sdst]);
        }
    };

    const int rsel = lane & 15, hi = (lane >> 4) * 8;
    const int xorc = (rsel & 7) << 3;   // read-side swizzle (row&7 == rsel&7 for all frags)

    stage(0, 0);
    const int NT = K >> 6;
    for (int t = 0; t < NT; ++t) {
        const int cur = t & 1;
        if (t + 1 < NT) {
            stage(cur ^ 1, t + 1);                    // 8 loads for tile t+1, stay in flight
            asm volatile("s_waitcnt vmcnt(8)" ::: "memory");   // tile t's 8 loads done
        } else {
            asm volatile("s_waitcnt vmcnt(0)" ::: "memory");
        }
        __builtin_amdgcn_s_barrier();                 // all threads' tile-t DMA visible
        __builtin_amdgcn_sched_barrier(0);
#pragma unroll
        for (int ph = 0; ph < 4; ++ph) {              // quadrant phases: mh in M, nh in N
            const int mh = ph >> 1, nh = ph & 1;
            short8 af[4][2], bg[2][2];
#pragma unroll
            for (int i = 0; i < 4; ++i) {
                const int row = wr * 128 + mh * 64 + i * 16 + rsel;
#pragma unroll
                for (int ks = 0; ks < 2; ++ks)
                    af[i][ks] = *(const short8*)&As[cur][row * 64 + ((ks * 32 + hi) ^ xorc)];
            }
#pragma unroll
            for (int i = 0; i < 2; ++i) {
                const int row = wc * 64 + nh * 32 + i * 16 + rsel;
#pragma unroll
                for (int ks = 0; ks < 2; ++ks)
                    bg[i][ks] = *(const short8*)&Bs[cur][row * 64 + ((ks * 32 + hi) ^ xorc)];
            }
            __builtin_amdgcn_s_setprio(1);
#pragma unroll
            for (int i = 0; i < 4; ++i)
#pragma unroll
                for (int jn = 0; jn < 2; ++jn)
#pragma unroll
                    for (int ks = 0; ks < 2; ++ks)
                        acc[mh * 4 + i][nh * 2 + jn] = __builtin_amdgcn_mfma_f32_16x16x32_bf16(
                            af[i][ks], bg[jn][ks], acc[mh * 4 + i][nh * 2 + jn], 0, 0, 0);
            __builtin_amdgcn_s_setprio(0);
            __builtin_amdgcn_sched_barrier(0);        // pin phase boundaries
        }
        __builtin_amdgcn_s_barrier();                 // all reads of cur done before reuse
        __builtin_amdgcn_sched_barrier(0);
    }

    const int rg = (lane >> 4) * 4;
    if (GLUE) {
        // pairs: (ni=2p) = a-block, (ni=2p+1) = g-block of the same 32-col group.
        __hip_bfloat16* Cb = (__hip_bfloat16*)Cout;
        const int No = N >> 1;
#pragma unroll
        for (int p = 0; p < 2; ++p) {
            int jcol = ((n0 + wc * 64) >> 1) + p * 16 + rsel;
            float ba = bias[jcol];
            float bgv = bias[Hn + jcol];
#pragma unroll
            for (int mi = 0; mi < 8; ++mi) {
                int row = m0 + wr * 128 + mi * 16 + rg;
                f32x4 va = acc[mi][2 * p], vg = acc[mi][2 * p + 1];
#pragma unroll
                for (int q = 0; q < 4; ++q) {
                    float a = va[q] + ba;
                    float g = vg[q] + bgv;
                    Cb[(long)(row + q) * No + jcol] = f2bf(a * (1.f / (1.f + __expf(-g))));
                }
            }
        }
        return;
    }
    float* Cf = (float*)Cout;
    __hip_bfloat16* Cb = (__hip_bfloat16*)Cout;
#pragma unroll
    for (int ni = 0; ni < 4; ++ni) {
        int col = n0 + wc * 64 + ni * 16 + rsel;
        if (NBOUND && col >= N) continue;
        float bi = bias ? bias[col] : 0.f;
#pragma unroll
        for (int mi = 0; mi < 8; ++mi) {
            int row = m0 + wr * 128 + mi * 16 + rg;
            f32x4 v = acc[mi][ni];
#pragma unroll
            for (int q = 0; q < 4; ++q) {
                long idx = (long)(row + q) * N + col;
                float x = v[q] + bi;
                if (OUTF32) Cf[idx] = x;
                else Cb[idx] = f2bf(x);
            }
        }
    }
}

// ---------------- launcher ----------------

extern "C" void kernel_launch(void* const* d_in, const int* in_sizes, int n_in,
                              void* d_out, int out_size, void* d_ws, size_t ws_size,
                              hipStream_t stream) {
    const int* tgt = (const int*)d_in[0];
    const float* enc_conved = (const float*)d_in[1];
    const float* enc_combined = (const float*)d_in[2];
    const float* tok_emb = (const float*)d_in[3];
    const float* pos_emb = (const float*)d_in[4];
    const float* w_e2h = (const float*)d_in[5];
    const float* b_e2h = (const float*)d_in[6];
    const float* w_h2e = (const float*)d_in[7];
    const float* b_h2e = (const float*)d_in[8];
    const float* w_ah2e = (const float*)d_in[9];
    const float* b_ah2e = (const float*)d_in[10];
    const float* w_ae2h = (const float*)d_in[11];
    const float* b_ae2h = (const float*)d_in[12];
    const float* w_fc = (const float*)d_in[13];
    const float* b_fc = (const float*)d_in[14];
    const float* conv_w = (const float*)d_in[15];
    const float* conv_b = (const float*)d_in[16];

    char* ws = (char*)d_ws;
    size_t off = 0;
    auto alloc = [&](size_t bytes) { size_t r = off; off = (off + bytes + 255) & ~(size_t)255; return r; };
    __hip_bfloat16* emb    = (__hip_bfloat16*)(ws + alloc((size_t)Mn * En * 2));        // 8.4 MB
    __hip_bfloat16* embA   = (__hip_bfloat16*)(ws + alloc((size_t)Mn * En * 2));        // 8.4 MB
    __hip_bfloat16* convin = (__hip_bfloat16*)(ws + alloc((size_t)Mn * Hn * 2));        // 16.8 MB
    __hip_bfloat16* conved = (__hip_bfloat16*)(ws + alloc((size_t)Mn * Hn * 2));        // 16.8 MB
    size_t o_en = alloc((size_t)Mn * Sn * 4);                                           // 16.8 MB
    float* energy = (float*)(ws + o_en);
    __hip_bfloat16* encm = (__hip_bfloat16*)(ws + o_en);   // overlay: prep-only bf16(enc_combined)
    __hip_bfloat16* attnbf = (__hip_bfloat16*)(ws + alloc((size_t)Mn * Sn * 2));        // 8.4 MB
    __hip_bfloat16* wT_e2h = (__hip_bfloat16*)(ws + alloc((size_t)Hn * En * 2));
    __hip_bfloat16* wT_h2e = (__hip_bfloat16*)(ws + alloc((size_t)En * Hn * 2));
    __hip_bfloat16* wT_ae2h= (__hip_bfloat16*)(ws + alloc((size_t)Hn * En * 2));
    __hip_bfloat16* wbAH   = (__hip_bfloat16*)(ws + alloc((size_t)Hn * En * 2));        // w_ah2e bf16 [H,E]
    __hip_bfloat16* wT_fc  = (__hip_bfloat16*)(ws + alloc((size_t)Vn * En * 2));        // 10.2 MB
    __hip_bfloat16* wpack  = (__hip_bfloat16*)(ws + alloc((size_t)2 * Hn * 3 * Hn * 2));// 12.6 MB
    __hip_bfloat16* encc   = (__hip_bfloat16*)(ws + alloc((size_t)Bn * Sn * En * 2));   // 8.4 MB
    __hip_bfloat16* encAH  = (__hip_bfloat16*)(ws + alloc((size_t)Bn * Sn * Hn * 2));   // 16.8 MB
    __hip_bfloat16* encCW  = (__hip_bfloat16*)(ws + alloc((size_t)Bn * Hn * Sn * 2));   // 16.8 MB
    float* embE            = (float*)(ws + alloc((size_t)Mn * Sn * 4));                 // 16.8 MB
    __hip_bfloat16* padrow = (__hip_bfloat16*)(ws + alloc(256));
    __hip_bfloat16* tmpE   = conved;  // overlay: conved dead after last attended GEMM

    float* out = (float*)d_out;
    float* attn_out = out + (long)Mn * Vn;
    const long bSq = (long)Sn * Sn;      // 262144
    const long bSH = (long)Sn * Hn;      // 524288

    dim3 tb(32, 8);
    const __hip_bfloat16* nb = nullptr;
    const float* nf = nullptr;

    // ---- prep ----
    padfill_kernel<<<1, 128, 0, stream>>>(padrow);
    embed_kernel<<<Mn, 128, 0, stream>>>(tgt, tok_emb, pos_emb, b_ah2e, emb, embA);
    transpose_f32_bf16<<<dim3(Hn / 32, En / 32, 1), tb, 0, stream>>>(w_e2h, wT_e2h, En, Hn, 0, 0);
    transpose_f32_bf16<<<dim3(En / 32, Hn / 32, 1), tb, 0, stream>>>(w_h2e, wT_h2e, Hn, En, 0, 0);
    transpose_f32_bf16<<<dim3(Hn / 32, En / 32, 1), tb, 0, stream>>>(w_ae2h, wT_ae2h, En, Hn, 0, 0);
    transpose_f32_bf16<<<dim3((Vn + 31) / 32, En / 32, 1), tb, 0, stream>>>(w_fc, wT_fc, En, Vn, 0, 0);
    convert_bf16_kernel<<<((long)Hn * En / 4 + 255) / 256, 256, 0, stream>>>(w_ah2e, wbAH, (long)Hn * En / 4);
    convert_bf16_kernel<<<((long)Bn * Sn * En / 4 + 255) / 256, 256, 0, stream>>>(enc_conved, encc, (long)Bn * Sn * En / 4);
    convert_bf16_kernel<<<((long)Bn * Sn * En / 4 + 255) / 256, 256, 0, stream>>>(enc_combined, encm, (long)Bn * Sn * En / 4);

    // encAH[b][s][h] = encc[b] @ w_ah2e^T   (layer-invariant attention factor)
    gemm_bf16<0, false, false><<<dim3(Hn / 128, Sn / 128, Bn), 256, 0, stream>>>(
        encc, wbAH, nullptr, encAH, nb, nb, nf, padrow, Sn, Hn, En, bSq, 0, bSH, 1.f, 1.f);
    // encCW[b][h][s] = (enc_combined[b] @ w_ae2h)^T
    gemm_bf16<0, false, false><<<dim3(Sn / 128, Hn / 128, Bn), 256, 0, stream>>>(
        wT_ae2h, encm, nullptr, encCW, nb, nb, nf, padrow, Hn, Sn, En, 0, bSq, bSH, 1.f, 1.f);
    // embE[b][t][s] = embA[b] @ encc[b]^T   (f32; kScale folded into embA)
    gemm_bf16<0, true, false><<<dim3(Sn / 128, Tn / 128, Bn), 256, 0, stream>>>(
        embA, encc, nullptr, embE, nb, nb, nf, padrow, Tn, Sn, En, bSq, bSq, bSq, 1.f, 1.f);
    // conv_input = embedded @ emb2hid + b       [8192,1024]
    gemm_bf16<0, false, false><<<dim3(Hn / 128, Mn / 128, 1), 256, 0, stream>>>(
        emb, wT_e2h, b_e2h, convin, nb, nb, nf, padrow, Mn, Hn, En, 0, 0, 0, 1.f, 1.f);

    for (int l = 0; l < Ln; ++l) {
        // pack conv weight (a/g interleaved for fused GLU)
        wpack_kernel<<<dim3(3 * Hn / 256, 2 * Hn, 1), 256, 0, stream>>>(conv_w, wpack, l);
        // conved = GLU(im2col(conv_input) @ wpack^T + conv_b[l])   [8192,1024] fused
        gemm256<false, true, true, false><<<dim3(2 * Hn / 256, Mn / 256, 1), 512, 0, stream>>>(
            convin, wpack, conv_b + (long)l * 2 * Hn, conved, padrow, Mn, 2 * Hn, 3 * Hn);
        // energy[b] = kScale * conved[b] @ encAH[b]^T(B-layout) + embE[b]   (f32)
        gemm_bf16<3, true, false><<<dim3(Sn / 128, Tn / 128, Bn), 256, 0, stream>>>(
            conved, encAH, nullptr, energy, nb, nb, embE, padrow,
            Tn, Sn, Hn, (long)Tn * Hn, bSH, bSq, kScale, 1.f);
        // attention = softmax(energy)  (f32 out only needed from the LAST layer)
        softmax_kernel<<<Mn, 256, 0, stream>>>(energy, (l == Ln - 1) ? attn_out : nullptr, attnbf);
        // conv_input = ((attn @ encCW + b_ae2h + conved)*s + conv_input)*s   (fused attended+ae2h)
        gemm_bf16<2, false, false><<<dim3(Hn / 128, Tn / 128, Bn), 256, 0, stream>>>(
            attnbf, encCW, b_ae2h, convin, conved, convin, nf, padrow,
            Tn, Hn, Sn, bSq, bSH, (long)Tn * Hn, kScale, kScale);
    }

    // conved = conv_input @ hid2emb + b   [8192,512]  (tmpE overlays conved)
    gemm_bf16<0, false, false><<<dim3(En / 128, Mn / 128, 1), 256, 0, stream>>>(
        convin, wT_h2e, b_h2e, tmpE, nb, nb, nf, padrow, Mn, En, Hn, 0, 0, 0, 1.f, 1.f);
    // output = conved @ fc_out + b        [8192,10000] f32, N-bounded  (256² pipeline)
    gemm256<true, false, false, true><<<dim3((Vn + 255) / 256, Mn / 256, 1), 512, 0, stream>>>(
        tmpE, wT_fc, b_fc, out, padrow, Mn, Vn, En);
}

// Round 6
// 1375.101 us; speedup vs baseline: 1.4998x; 1.0273x over previous
//
#include <hip/hip_runtime.h>
#include <hip/hip_bf16.h>

typedef __attribute__((ext_vector_type(4))) float f32x4;
typedef __attribute__((ext_vector_type(8))) short short8;

#define DEVFN __device__ __forceinline__

static constexpr int Bn = 16, Tn = 512, Sn = 512, Vn = 10000, En = 512, Hn = 1024, Ln = 6;
static constexpr int Mn = Bn * Tn;  // 8192 token rows
static constexpr float kScale = 0.70710678118654752440f;

DEVFN float bf2f(__hip_bfloat16 x) { return __bfloat162float(x); }
DEVFN __hip_bfloat16 f2bf(float x) { return __float2bfloat16(x); }

struct bf16x4 { __hip_bfloat16 x, y, z, w; };

// async global -> LDS, 16B per lane (wave-uniform LDS base + lane*16 layout)
DEVFN void gload_lds16(const short* g, short* l) {
    __builtin_amdgcn_global_load_lds((const __attribute__((address_space(1))) void*)g,
                                     (__attribute__((address_space(3))) void*)l, 16, 0, 0);
}

// ---------------- small prep kernels ----------------

__global__ void padfill_kernel(__hip_bfloat16* p) {
    p[threadIdx.x] = f2bf(1.0f);  // PAD_VAL as float, per torch code
}

// embedded[b,t,:] = tok_emb[tgt[b,t],:] + pos_emb[t,:]  (bf16)
// embA = kScale*(embedded + b_ah2e)                      (bf16, for embE precompute)
__global__ void embed_kernel(const int* __restrict__ tgt, const float* __restrict__ tok,
                             const float* __restrict__ pos, const float* __restrict__ bah,
                             __hip_bfloat16* __restrict__ out, __hip_bfloat16* __restrict__ outA) {
    int row = blockIdx.x;              // 0..8191
    int t = row & (Tn - 1);
    int v = tgt[row];
    const float* tr = tok + (long)v * En;
    const float* pr = pos + (long)t * En;
    int e = threadIdx.x * 4;           // block 128 covers 512
    float4 a = *(const float4*)(tr + e);
    float4 b = *(const float4*)(pr + e);
    float4 bb = *(const float4*)(bah + e);
    bf16x4 o{f2bf(a.x + b.x), f2bf(a.y + b.y), f2bf(a.z + b.z), f2bf(a.w + b.w)};
    *(bf16x4*)(out + (long)row * En + e) = o;
    bf16x4 oa{f2bf(kScale * (a.x + b.x + bb.x)), f2bf(kScale * (a.y + b.y + bb.y)),
              f2bf(kScale * (a.z + b.z + bb.z)), f2bf(kScale * (a.w + b.w + bb.w))};
    *(bf16x4*)(outA + (long)row * En + e) = oa;
}

// dst[c][r] = bf16(src[r][c]); src is [R][C] f32. grid(ceil(C/32), ceil(R/32), Z), block(32,8)
__global__ void transpose_f32_bf16(const float* __restrict__ src, __hip_bfloat16* __restrict__ dst,
                                   int R, int C, long sZi, long sZo) {
    __shared__ float tile[32][33];
    src += (long)blockIdx.z * sZi;
    dst += (long)blockIdx.z * sZo;
    int c0 = blockIdx.x * 32, r0 = blockIdx.y * 32;
    for (int i = threadIdx.y; i < 32; i += 8) {
        int r = r0 + i, c = c0 + threadIdx.x;
        tile[i][threadIdx.x] = (r < R && c < C) ? src[(long)r * C + c] : 0.f;
    }
    __syncthreads();
    for (int i = threadIdx.y; i < 32; i += 8) {
        int c = c0 + i, r = r0 + threadIdx.x;
        if (c < C && r < R) dst[(long)c * R + r] = f2bf(tile[threadIdx.x][i]);
    }
}

// plain f32 -> bf16 convert (n divisible by 4)
__global__ void convert_bf16_kernel(const float* __restrict__ src, __hip_bfloat16* __restrict__ dst, long n4) {
    long i = (long)blockIdx.x * blockDim.x + threadIdx.x;
    if (i >= n4) return;
    long j = i * 4;
    float4 v = *(const float4*)(src + j);
    bf16x4 o{f2bf(v.x), f2bf(v.y), f2bf(v.z), f2bf(v.w)};
    *(bf16x4*)(dst + j) = o;
}

// conv weight pack for layer l, a/g interleaved in 16-col blocks for fused GLU:
// packed col c: grp=c>>5, w=c&31; o = w<16 ? grp*16+w : H + grp*16 + (w-16)
// wp[c][tap*H+i] = bf16(conv_w[l][o][i][tap]).  grid(12, 2048), block 256.
__global__ void wpack_kernel(const float* __restrict__ convw, __hip_bfloat16* __restrict__ wp, int l) {
    int kk = blockIdx.x * 256 + threadIdx.x;  // 0..3071
    int c = blockIdx.y;                        // 0..2047 packed col
    int grp = c >> 5, w = c & 31;
    int o = (w < 16) ? grp * 16 + w : Hn + grp * 16 + (w - 16);
    int i = kk & (Hn - 1);
    int tap = kk >> 10;
    long base = ((long)(l * 2 * Hn + o)) * (Hn * 3);
    wp[(long)c * (3 * Hn) + kk] = f2bf(convw[base + (long)i * 3 + tap]);
}

// row softmax over S=512; writes bf16 (next GEMM input) + optional f32 (final attention)
__global__ __launch_bounds__(256) void softmax_kernel(const float* __restrict__ energy,
                                                      float* __restrict__ attn_f32,
                                                      __hip_bfloat16* __restrict__ attn_bf) {
    int row = blockIdx.x;  // 0..8191
    const float* e = energy + (long)row * Sn;
    int tid = threadIdx.x;
    float v0 = e[tid], v1 = e[tid + 256];
    float m = fmaxf(v0, v1);
    for (int off = 32; off; off >>= 1) m = fmaxf(m, __shfl_xor(m, off));
    __shared__ float redm[4];
    __shared__ float reds[4];
    int lane = tid & 63, w = tid >> 6;
    if (lane == 0) redm[w] = m;
    __syncthreads();
    m = fmaxf(fmaxf(redm[0], redm[1]), fmaxf(redm[2], redm[3]));
    float x0 = __expf(v0 - m), x1 = __expf(v1 - m);
    float s = x0 + x1;
    for (int off = 32; off; off >>= 1) s += __shfl_xor(s, off);
    if (lane == 0) reds[w] = s;
    __syncthreads();
    s = reds[0] + reds[1] + reds[2] + reds[3];
    float inv = 1.f / s;
    long base = (long)row * Sn;
    if (attn_f32) {
        attn_f32[base + tid] = x0 * inv;
        attn_f32[base + tid + 256] = x1 * inv;
    }
    attn_bf[base + tid] = f2bf(x0 * inv);
    attn_bf[base + tid + 256] = f2bf(x1 * inv);
}

// ---------------- 128x128 2-phase GEMM ----------------
// C[M,N] = A[M,K] @ Bw[N,K]^T.  EPI: 0: x=acc+bias; 2: x=((acc+bias+R1)*s1+R2)*s2;
// 3: x=acc*s1 + R1f[idx].  R1/R2/R1f batch-offset by z*cZ.
template <int EPI, bool OUTF32, bool NBOUND>
__global__ __launch_bounds__(256) void gemm_bf16(
    const __hip_bfloat16* __restrict__ A, const __hip_bfloat16* __restrict__ Bw,
    const float* __restrict__ bias, void* __restrict__ Cout,
    const __hip_bfloat16* __restrict__ R1, const __hip_bfloat16* __restrict__ R2,
    const float* __restrict__ R1f, const __hip_bfloat16* __restrict__ padrow,
    int M, int N, int K, long aZ, long bZ, long cZ, float s1, float s2) {
    __shared__ alignas(16) short As[2][128 * 32];
    __shared__ alignas(16) short Bs[2][128 * 32];
    const int tid = threadIdx.x;
    const int lane = tid & 63;
    const int wid = tid >> 6;
    const int wr = wid >> 1, wc = wid & 1;
    const int m0 = blockIdx.y * 128, n0 = blockIdx.x * 128;
    const short* Ag = (const short*)A + (long)blockIdx.z * aZ;
    const short* Bg = (const short*)Bw + (long)blockIdx.z * bZ;
    const short* pad = (const short*)padrow;

    f32x4 acc[4][4] = {};

    const int rc = tid >> 2;        // staging row (j=0); LDS byte off = tid*16 (linear)
    const int k8 = (tid & 3) * 8;   // element offset within the 32-wide row

    auto stage = [&](int buf, int k0) {
#pragma unroll
        for (int j = 0; j < 2; ++j) {
            int r = rc + j * 64;
            const short* asrc = Ag + (long)(m0 + r) * K + k0 + k8;
            gload_lds16(asrc, &As[buf][r * 32 + k8]);
            int n = n0 + r;
            const short* bsrc = (NBOUND && n >= N) ? (pad + k8) : (Bg + (long)n * K + k0 + k8);
            gload_lds16(bsrc, &Bs[buf][r * 32 + k8]);
        }
    };

    stage(0, 0);
    __syncthreads();

    int cur = 0;
    for (int k0 = 0; k0 < K; k0 += 32) {
        if (k0 + 32 < K) stage(cur ^ 1, k0 + 32);   // issue next-tile loads (in flight over MFMA)
        const int rsel = lane & 15, hi = (lane >> 4) * 8;
        short8 af[4], bg[4];
#pragma unroll
        for (int mi = 0; mi < 4; ++mi)
            af[mi] = *(const short8*)&As[cur][(wr * 64 + mi * 16 + rsel) * 32 + hi];
#pragma unroll
        for (int ni = 0; ni < 4; ++ni)
            bg[ni] = *(const short8*)&Bs[cur][(wc * 64 + ni * 16 + rsel) * 32 + hi];
#pragma unroll
        for (int mi = 0; mi < 4; ++mi)
#pragma unroll
            for (int ni = 0; ni < 4; ++ni)
                acc[mi][ni] = __builtin_amdgcn_mfma_f32_16x16x32_bf16(af[mi], bg[ni], acc[mi][ni], 0, 0, 0);
        __syncthreads();  // vmcnt(0)+lgkmcnt(0)+barrier: next tile staged, reads of cur done
        cur ^= 1;
    }

    const int rsel = lane & 15, rg = (lane >> 4) * 4;
    float* Cf = (float*)Cout + (long)blockIdx.z * cZ;
    __hip_bfloat16* Cb = (__hip_bfloat16*)Cout + (long)blockIdx.z * cZ;
    const __hip_bfloat16* R1z = R1 + (long)blockIdx.z * cZ;
    const __hip_bfloat16* R2z = R2 + (long)blockIdx.z * cZ;
    const float* R1fz = R1f + (long)blockIdx.z * cZ;
#pragma unroll
    for (int ni = 0; ni < 4; ++ni) {
        int col = n0 + wc * 64 + ni * 16 + rsel;
        if (NBOUND && col >= N) continue;
        float bi = (EPI != 3 && bias) ? bias[col] : 0.f;
#pragma unroll
        for (int mi = 0; mi < 4; ++mi) {
            int row = m0 + wr * 64 + mi * 16 + rg;
            f32x4 v = acc[mi][ni];
#pragma unroll
            for (int q = 0; q < 4; ++q) {
                long idx = (long)(row + q) * N + col;
                float x;
                if (EPI == 3) x = v[q] * s1 + R1fz[idx];
                else {
                    x = v[q] + bi;
                    if (EPI >= 1) x = (x + bf2f(R1z[idx])) * s1;
                    if (EPI >= 2) x = (x + bf2f(R2z[idx])) * s2;
                }
                if (OUTF32) Cf[idx] = x;
                else Cb[idx] = f2bf(x);
            }
        }
    }
}

// ---------------- 256x256 deep-pipeline GEMM (conv + fc_out) ----------------
// T1 XCD-swizzle + T2 LDS-swizzle (both-sides involution) + T3/T4 counted vmcnt(8)
// double-buffer + T5 setprio. 8 waves (2Mx4N), BK=64.
// Dedup'd fragment reads: 24 ds_read_b128 / wave / K-tile (bg both halves held in
// registers; af per mh-half) — halves LDS traffic vs quadrant re-reads.
// GLUE: a/g channel pairs interleaved in 16-col blocks (wpack); epilogue computes
// (a+ba)*sigmoid(g+bg) and writes [M][N/2] bf16.
template <bool OUTF32, bool GLUE, bool IM2COL, bool NBOUND>
__global__ __launch_bounds__(512, 2) void gemm256(
    const __hip_bfloat16* __restrict__ A, const __hip_bfloat16* __restrict__ Bw,
    const float* __restrict__ bias, void* __restrict__ Cout,
    const __hip_bfloat16* __restrict__ padrow, int M, int N, int K) {
    __shared__ alignas(16) short As[2][256 * 64];
    __shared__ alignas(16) short Bs[2][256 * 64];
    const int tid = threadIdx.x;
    const int lane = tid & 63;
    const int wid = tid >> 6;
    const int wr = wid >> 2, wc = wid & 3;
    // T1: bijective XCD swizzle (m204) on the linearized block id
    const int nwg = gridDim.x * gridDim.y;
    const int orig = blockIdx.y * gridDim.x + blockIdx.x;
    const int qd = nwg >> 3, rd = nwg & 7, xc = orig & 7, loc = orig >> 3;
    const int bid = (xc < rd ? xc * (qd + 1) : rd * (qd + 1) + (xc - rd) * qd) + loc;
    const int n0 = (bid % gridDim.x) * 256, m0 = (bid / gridDim.x) * 256;
    const short* Ag = (const short*)A;
    const short* Bg = (const short*)Bw;
    const short* pad = (const short*)padrow;

    f32x4 acc[8][4] = {};

    const int srow_l = tid >> 3;        // staging row low bits (j*64 + srow_l)
    const int scol = ((tid & 7) ^ (srow_l & 7)) * 8;  // inverse-swizzled global col (shorts)
    const int sdst = (tid >> 3) * 64 + (tid & 7) * 8; // linear LDS dst = tid*8 elems

    auto stage = [&](int buf, int kt) {
        const int k0 = kt * 64;
#pragma unroll
        for (int j = 0; j < 4; ++j) {
            const int row = j * 64 + srow_l;
            const short* asrc;
            if (IM2COL) {
                int m = m0 + row;
                int t = m & (Tn - 1);
                int tap = k0 >> 10;                 // uniform per K-tile (1024 % 64 == 0)
                int tau = t - 2 + tap;
                int kcol = (k0 & (Hn - 1)) + scol;
                asrc = (tau >= 0) ? (Ag + (long)(m - 2 + tap) * Hn + kcol) : (pad + scol);
            } else {
                asrc = Ag + (long)(m0 + row) * K + k0 + scol;
            }
            gload_lds16(asrc, &As[buf][j * 4096 + sdst]);
            int n = n0 + row;
            const short* bsrc = (NBOUND && n >= N) ? (pad + scol) : (Bg + (long)n * K + k0 + scol);
            gload_lds16(bsrc, &Bs[buf][j * 4096 + sdst]);
        }
    };

    const int rsel = lane & 15, hi = (lane >> 4) * 8;
    const int xorc = (rsel & 7) << 3;   // read-side swizzle (row&7 == rsel&7 for all frags)

    stage(0, 0);
    const int NT = K >> 6;
    for (int t = 0; t < NT; ++t) {
        const int cur = t & 1;
        if (t + 1 < NT) {
            stage(cur ^ 1, t + 1);                    // 8 loads for tile t+1, stay in flight
            asm volatile("s_waitcnt vmcnt(8)" ::: "memory");   // tile t's 8 loads done
        } else {
            asm volatile("s_waitcnt vmcnt(0)" ::: "memory");
        }
        __builtin_amdgcn_s_barrier();                 // all threads' tile-t DMA visible
        __builtin_amdgcn_sched_barrier(0);
        // B fragments for BOTH nh halves, read once per K-tile (8 x ds_read_b128)
        short8 bg[2][2][2];
#pragma unroll
        for (int nh = 0; nh < 2; ++nh)
#pragma unroll
            for (int i = 0; i < 2; ++i) {
                const int row = wc * 64 + nh * 32 + i * 16 + rsel;
#pragma unroll
                for (int ks = 0; ks < 2; ++ks)
                    bg[nh][i][ks] = *(const short8*)&Bs[cur][row * 64 + ((ks * 32 + hi) ^ xorc)];
            }
#pragma unroll
        for (int mh = 0; mh < 2; ++mh) {              // A fragments per mh-half (8 reads)
            short8 af[4][2];
#pragma unroll
            for (int i = 0; i < 4; ++i) {
                const int row = wr * 128 + mh * 64 + i * 16 + rsel;
#pragma unroll
                for (int ks = 0; ks < 2; ++ks)
                    af[i][ks] = *(const short8*)&As[cur][row * 64 + ((ks * 32 + hi) ^ xorc)];
            }
            __builtin_amdgcn_s_setprio(1);
#pragma unroll
            for (int nh = 0; nh < 2; ++nh)
#pragma unroll
                for (int i = 0; i < 4; ++i)
#pragma unroll
                    for (int jn = 0; jn < 2; ++jn)
#pragma unroll
                        for (int ks = 0; ks < 2; ++ks)
                            acc[mh * 4 + i][nh * 2 + jn] = __builtin_amdgcn_mfma_f32_16x16x32_bf16(
                                af[i][ks], bg[nh][jn][ks], acc[mh * 4 + i][nh * 2 + jn], 0, 0, 0);
            __builtin_amdgcn_s_setprio(0);
            __builtin_amdgcn_sched_barrier(0);        // pin mh-section boundaries
        }
        __builtin_amdgcn_s_barrier();                 // all reads of cur done before reuse
        __builtin_amdgcn_sched_barrier(0);
    }

    const int rg = (lane >> 4) * 4;
    if (GLUE) {
        // pairs: (ni=2p) = a-block, (ni=2p+1) = g-block of the same 32-col group.
        __hip_bfloat16* Cb = (__hip_bfloat16*)Cout;
        const int No = N >> 1;
#pragma unroll
        for (int p = 0; p < 2; ++p) {
            int jcol = ((n0 + wc * 64) >> 1) + p * 16 + rsel;
            float ba = bias[jcol];
            float bgv = bias[Hn + jcol];
#pragma unroll
            for (int mi = 0; mi < 8; ++mi) {
                int row = m0 + wr * 128 + mi * 16 + rg;
                f32x4 va = acc[mi][2 * p], vg = acc[mi][2 * p + 1];
#pragma unroll
                for (int q = 0; q < 4; ++q) {
                    float a = va[q] + ba;
                    float g = vg[q] + bgv;
                    Cb[(long)(row + q) * No + jcol] = f2bf(a * (1.f / (1.f + __expf(-g))));
                }
            }
        }
        return;
    }
    float* Cf = (float*)Cout;
    __hip_bfloat16* Cb = (__hip_bfloat16*)Cout;
#pragma unroll
    for (int ni = 0; ni < 4; ++ni) {
        int col = n0 + wc * 64 + ni * 16 + rsel;
        if (NBOUND && col >= N) continue;
        float bi = bias ? bias[col] : 0.f;
#pragma unroll
        for (int mi = 0; mi < 8; ++mi) {
            int row = m0 + wr * 128 + mi * 16 + rg;
            f32x4 v = acc[mi][ni];
#pragma unroll
            for (int q = 0; q < 4; ++q) {
                long idx = (long)(row + q) * N + col;
                float x = v[q] + bi;
                if (OUTF32) Cf[idx] = x;
                else Cb[idx] = f2bf(x);
            }
        }
    }
}

// ---------------- launcher ----------------

extern "C" void kernel_launch(void* const* d_in, const int* in_sizes, int n_in,
                              void* d_out, int out_size, void* d_ws, size_t ws_size,
                              hipStream_t stream) {
    const int* tgt = (const int*)d_in[0];
    const float* enc_conved = (const float*)d_in[1];
    const float* enc_combined = (const float*)d_in[2];
    const float* tok_emb = (const float*)d_in[3];
    const float* pos_emb = (const float*)d_in[4];
    const float* w_e2h = (const float*)d_in[5];
    const float* b_e2h = (const float*)d_in[6];
    const float* w_h2e = (const float*)d_in[7];
    const float* b_h2e = (const float*)d_in[8];
    const float* w_ah2e = (const float*)d_in[9];
    const float* b_ah2e = (const float*)d_in[10];
    const float* w_ae2h = (const float*)d_in[11];
    const float* b_ae2h = (const float*)d_in[12];
    const float* w_fc = (const float*)d_in[13];
    const float* b_fc = (const float*)d_in[14];
    const float* conv_w = (const float*)d_in[15];
    const float* conv_b = (const float*)d_in[16];

    char* ws = (char*)d_ws;
    size_t off = 0;
    auto alloc = [&](size_t bytes) { size_t r = off; off = (off + bytes + 255) & ~(size_t)255; return r; };
    __hip_bfloat16* emb    = (__hip_bfloat16*)(ws + alloc((size_t)Mn * En * 2));        // 8.4 MB
    __hip_bfloat16* embA   = (__hip_bfloat16*)(ws + alloc((size_t)Mn * En * 2));        // 8.4 MB
    __hip_bfloat16* convin = (__hip_bfloat16*)(ws + alloc((size_t)Mn * Hn * 2));        // 16.8 MB
    __hip_bfloat16* conved = (__hip_bfloat16*)(ws + alloc((size_t)Mn * Hn * 2));        // 16.8 MB
    size_t o_en = alloc((size_t)Mn * Sn * 4);                                           // 16.8 MB
    float* energy = (float*)(ws + o_en);
    __hip_bfloat16* encm = (__hip_bfloat16*)(ws + o_en);   // overlay: prep-only bf16(enc_combined)
    __hip_bfloat16* attnbf = (__hip_bfloat16*)(ws + alloc((size_t)Mn * Sn * 2));        // 8.4 MB
    __hip_bfloat16* wT_e2h = (__hip_bfloat16*)(ws + alloc((size_t)Hn * En * 2));
    __hip_bfloat16* wT_h2e = (__hip_bfloat16*)(ws + alloc((size_t)En * Hn * 2));
    __hip_bfloat16* wT_ae2h= (__hip_bfloat16*)(ws + alloc((size_t)Hn * En * 2));
    __hip_bfloat16* wbAH   = (__hip_bfloat16*)(ws + alloc((size_t)Hn * En * 2));        // w_ah2e bf16 [H,E]
    __hip_bfloat16* wT_fc  = (__hip_bfloat16*)(ws + alloc((size_t)Vn * En * 2));        // 10.2 MB
    __hip_bfloat16* wpack  = (__hip_bfloat16*)(ws + alloc((size_t)2 * Hn * 3 * Hn * 2));// 12.6 MB
    __hip_bfloat16* encc   = (__hip_bfloat16*)(ws + alloc((size_t)Bn * Sn * En * 2));   // 8.4 MB
    __hip_bfloat16* encAH  = (__hip_bfloat16*)(ws + alloc((size_t)Bn * Sn * Hn * 2));   // 16.8 MB
    __hip_bfloat16* encCW  = (__hip_bfloat16*)(ws + alloc((size_t)Bn * Hn * Sn * 2));   // 16.8 MB
    float* embE            = (float*)(ws + alloc((size_t)Mn * Sn * 4));                 // 16.8 MB
    __hip_bfloat16* padrow = (__hip_bfloat16*)(ws + alloc(256));
    __hip_bfloat16* tmpE   = conved;  // overlay: conved dead after last attended GEMM

    float* out = (float*)d_out;
    float* attn_out = out + (long)Mn * Vn;
    const long bSq = (long)Sn * Sn;      // 262144
    const long bSH = (long)Sn * Hn;      // 524288

    dim3 tb(32, 8);
    const __hip_bfloat16* nb = nullptr;
    const float* nf = nullptr;

    // ---- prep ----
    padfill_kernel<<<1, 128, 0, stream>>>(padrow);
    embed_kernel<<<Mn, 128, 0, stream>>>(tgt, tok_emb, pos_emb, b_ah2e, emb, embA);
    transpose_f32_bf16<<<dim3(Hn / 32, En / 32, 1), tb, 0, stream>>>(w_e2h, wT_e2h, En, Hn, 0, 0);
    transpose_f32_bf16<<<dim3(En / 32, Hn / 32, 1), tb, 0, stream>>>(w_h2e, wT_h2e, Hn, En, 0, 0);
    transpose_f32_bf16<<<dim3(Hn / 32, En / 32, 1), tb, 0, stream>>>(w_ae2h, wT_ae2h, En, Hn, 0, 0);
    transpose_f32_bf16<<<dim3((Vn + 31) / 32, En / 32, 1), tb, 0, stream>>>(w_fc, wT_fc, En, Vn, 0, 0);
    convert_bf16_kernel<<<((long)Hn * En / 4 + 255) / 256, 256, 0, stream>>>(w_ah2e, wbAH, (long)Hn * En / 4);
    convert_bf16_kernel<<<((long)Bn * Sn * En / 4 + 255) / 256, 256, 0, stream>>>(enc_conved, encc, (long)Bn * Sn * En / 4);
    convert_bf16_kernel<<<((long)Bn * Sn * En / 4 + 255) / 256, 256, 0, stream>>>(enc_combined, encm, (long)Bn * Sn * En / 4);

    // encAH[b][s][h] = encc[b] @ w_ah2e^T   (layer-invariant attention factor)
    gemm_bf16<0, false, false><<<dim3(Hn / 128, Sn / 128, Bn), 256, 0, stream>>>(
        encc, wbAH, nullptr, encAH, nb, nb, nf, padrow, Sn, Hn, En, bSq, 0, bSH, 1.f, 1.f);
    // encCW[b][h][s] = (enc_combined[b] @ w_ae2h)^T
    gemm_bf16<0, false, false><<<dim3(Sn / 128, Hn / 128, Bn), 256, 0, stream>>>(
        wT_ae2h, encm, nullptr, encCW, nb, nb, nf, padrow, Hn, Sn, En, 0, bSq, bSH, 1.f, 1.f);
    // embE[b][t][s] = embA[b] @ encc[b]^T   (f32; kScale folded into embA)
    gemm_bf16<0, true, false><<<dim3(Sn / 128, Tn / 128, Bn), 256, 0, stream>>>(
        embA, encc, nullptr, embE, nb, nb, nf, padrow, Tn, Sn, En, bSq, bSq, bSq, 1.f, 1.f);
    // conv_input = embedded @ emb2hid + b       [8192,1024]
    gemm_bf16<0, false, false><<<dim3(Hn / 128, Mn / 128, 1), 256, 0, stream>>>(
        emb, wT_e2h, b_e2h, convin, nb, nb, nf, padrow, Mn, Hn, En, 0, 0, 0, 1.f, 1.f);

    for (int l = 0; l < Ln; ++l) {
        // pack conv weight (a/g interleaved for fused GLU)
        wpack_kernel<<<dim3(3 * Hn / 256, 2 * Hn, 1), 256, 0, stream>>>(conv_w, wpack, l);
        // conved = GLU(im2col(conv_input) @ wpack^T + conv_b[l])   [8192,1024] fused
        gemm256<false, true, true, false><<<dim3(2 * Hn / 256, Mn / 256, 1), 512, 0, stream>>>(
            convin, wpack, conv_b + (long)l * 2 * Hn, conved, padrow, Mn, 2 * Hn, 3 * Hn);
        // energy[b] = kScale * conved[b] @ encAH[b]^T(B-layout) + embE[b]   (f32)
        gemm_bf16<3, true, false><<<dim3(Sn / 128, Tn / 128, Bn), 256, 0, stream>>>(
            conved, encAH, nullptr, energy, nb, nb, embE, padrow,
            Tn, Sn, Hn, (long)Tn * Hn, bSH, bSq, kScale, 1.f);
        // attention = softmax(energy)  (f32 out only needed from the LAST layer)
        softmax_kernel<<<Mn, 256, 0, stream>>>(energy, (l == Ln - 1) ? attn_out : nullptr, attnbf);
        // conv_input = ((attn @ encCW + b_ae2h + conved)*s + conv_input)*s   (fused attended+ae2h)
        gemm_bf16<2, false, false><<<dim3(Hn / 128, Tn / 128, Bn), 256, 0, stream>>>(
            attnbf, encCW, b_ae2h, convin, conved, convin, nf, padrow,
            Tn, Hn, Sn, bSq, bSH, (long)Tn * Hn, kScale, kScale);
    }

    // conved = conv_input @ hid2emb + b   [8192,512]  (tmpE overlays conved)
    gemm_bf16<0, false, false><<<dim3(En / 128, Mn / 128, 1), 256, 0, stream>>>(
        convin, wT_h2e, b_h2e, tmpE, nb, nb, nf, padrow, Mn, En, Hn, 0, 0, 0, 1.f, 1.f);
    // output = conved @ fc_out + b        [8192,10000] f32, N-bounded  (256² pipeline)
    gemm256<true, false, false, true><<<dim3((Vn + 255) / 256, Mn / 256, 1), 512, 0, stream>>>(
        tmpE, wT_fc, b_fc, out, padrow, Mn, Vn, En);
}